// Round 11
// baseline (410.162 us; speedup 1.0000x reference)
//
#include <hip/hip_runtime.h>
#include <hip/hip_bf16.h>

#define B_ 2048
#define EPSF 1e-5f

typedef __attribute__((ext_vector_type(8))) short short8v;
typedef __attribute__((ext_vector_type(4))) short short4v;
typedef __attribute__((ext_vector_type(4))) float f32x4;

// float -> bf16 bits via compiler-native conversion
__device__ __forceinline__ short f2bf_s(float f) {
  __hip_bfloat16 h = __float2bfloat16(f);
  return *reinterpret_cast<const short*>(&h);
}
__device__ __forceinline__ float bf2f(short s) {
  return __uint_as_float(((unsigned)(unsigned short)s) << 16);
}

// ---------------- weight prep -------------------------------------------------
__global__ __launch_bounds__(256) void k_prep(
    const float* __restrict__ f1_w, const float* __restrict__ fpw_w,
    const float* __restrict__ f2_w, const float* __restrict__ qkv_pw,
    const float* __restrict__ lin_w, const float* __restrict__ fdw_w,
    const float* __restrict__ fdw_b, const float* __restrict__ f_bng,
    const float* __restrict__ f_bnb, const float* __restrict__ f_bnm,
    const float* __restrict__ f_bnv, const float* __restrict__ qkv_dw,
    const float* __restrict__ qkv_bng, const float* __restrict__ qkv_bnb,
    const float* __restrict__ qkv_bnm, const float* __restrict__ qkv_bnv,
    short* __restrict__ qkvA, short* __restrict__ linb,
    short* __restrict__ f1wb, short* __restrict__ img,
    float* __restrict__ convW, float* __restrict__ convB,
    float* __restrict__ qkvdw, float* __restrict__ qkvdb) {
  int i = blockIdx.x * 256 + threadIdx.x;
  if (i < 7680) {
    int l = i / 3840, r = i % 3840;
    int io = r / 40, c = r % 40;
    qkvA[i] = (c < 32) ? f2bf_s(qkv_pw[l * 3072 + io * 32 + c]) : (short)0;
  }
  if (i < 262144) linb[i] = f2bf_s(lin_w[i]);
  if (i < 10240) {
    int l = i / 5120, r = i % 5120, o = r / 40, kk = r % 40;
    f1wb[i] = (kk < 32) ? f2bf_s(f1_w[l * 4096 + o * 32 + kk]) : (short)0;
  }
  if (i < 48640) {
    int l = i / 24320, r = i % 24320;
    short val;
    if (r < 19456) {
      int o = r / 152, kk = r % 152;
      val = (kk < 128) ? f2bf_s(fpw_w[l * 16384 + o * 128 + kk]) : (short)0;
    } else {
      int r2 = r - 19456;
      int d = r2 / 152, kk = r2 % 152;
      val = (kk < 128) ? f2bf_s(f2_w[l * 4096 + d * 128 + kk]) : (short)0;
    }
    img[i] = val;
  }
  if (i < 256) {
    int l = i >> 7, c = i & 127;
    float scale = f_bng[l * 128 + c] * rsqrtf(f_bnv[l * 128 + c] + EPSF);
#pragma unroll
    for (int k = 0; k < 9; k++)
      convW[l * 1152 + k * 128 + c] = fdw_w[(l * 128 + c) * 9 + k] * scale;
    convB[l * 128 + c] =
        (fdw_b[l * 128 + c] - f_bnm[l * 128 + c]) * scale + f_bnb[l * 128 + c];
  }
  if (i < 192) {  // qkv conv BN fold: [l][3][9][32] + [l][3][32]
    int l = i / 96, iw = (i % 96) / 32, c = i % 32;
    int bi = l * 96 + iw * 32 + c;
    float scale = qkv_bng[bi] * rsqrtf(qkv_bnv[bi] + EPSF);
#pragma unroll
    for (int k = 0; k < 9; k++)
      qkvdw[((l * 3 + iw) * 9 + k) * 32 + c] =
          qkv_dw[(l * 96 + iw * 32 + c) * 9 + k] * scale;
    qkvdb[bi] = qkv_bnb[bi] - qkv_bnm[bi] * scale;
  }
}

// ---------------- K_ATT2: 2 samples/block, 1024 threads, LDS 93184 -----------
// Per-sample LDS (46592 B), sample s at base s*46592:
//   pbf  [32][264] bf16 @0      (16896)   -- LN1 patches; overlays after conv:
//       sc fp32 [32][33] @0     (4224)
//       pa  [32][40]  @4224     (2560)
//       ore [8][264]  @6784     (4224)
//   t3s [3][64][40] @16896      (15360)   -- overlay: xc1 [16][264] @16896
//   qe  [32][72]  @32256        (4608)
//   ke  [32][72]  @36864        (4608)
//   vt  [64][40]  @41472        (5120)
__global__ __launch_bounds__(1024, 4) void k_att2(
    const float* __restrict__ xin, const float* __restrict__ g,
    const float* __restrict__ beta, const float* __restrict__ qkvdw,
    const float* __restrict__ qkvdb, const short* __restrict__ qkvA,
    const float* __restrict__ posn, const float* __restrict__ c1w,
    const float* __restrict__ c1b, const short* __restrict__ linb,
    const float* __restrict__ lin_b, float* __restrict__ xout) {
  __shared__ __align__(16) char smem[93184];
  int tid = threadIdx.x;
  int lane = tid & 63, wid = tid >> 6;          // wid 0..15
  int s = wid >> 3, w8 = wid & 7;               // sample half, wave-in-half
  int row = lane & 15, kg = lane >> 4;
  int tid511 = tid & 511;

  char* sb = smem + s * 46592;
  float* sc  = (float*)sb;
  short* pbf = (short*)sb;
  short* pa  = (short*)(sb + 4224);
  short* ore = (short*)(sb + 6784);
  short* t3s = (short*)(sb + 16896);
  short* xc1 = (short*)(sb + 16896);
  short* qe  = (short*)(sb + 32256);
  short* ke  = (short*)(sb + 36864);
  short* vt  = (short*)(sb + 41472);

  int b = blockIdx.x * 2 + s;
  const float* xb = xin + (size_t)b * 8192;
  float* xo = xout + (size_t)b * 8192;

  // ---- early prefetches ----
  float xr[4][4];
#pragma unroll
  for (int t = 0; t < 4; t++)
#pragma unroll
    for (int r = 0; r < 4; r++)
      xr[t][r] = xb[(kg * 4 + r) * 512 + (w8 * 4 + t) * 16 + row];
  int mi_pw = w8 & 1;
  short8v aq[3];
#pragma unroll
  for (int iw = 0; iw < 3; iw++)
    aq[iw] = *(const short8v*)&qkvA[(iw * 32 + mi_pw * 16 + row) * 40 + kg * 8];

  // ---- LN1 + to_patches -> pbf bf16 (2 rows per wave-in-half) ----
  for (int r = w8; r < 16; r += 8) {
    float vals[8];
    float sm = 0.f, ss = 0.f;
#pragma unroll
    for (int j = 0; j < 8; j++) {
      float t = xb[r * 512 + lane + j * 64];
      vals[j] = t; sm += t; ss += t * t;
    }
#pragma unroll
    for (int o = 32; o; o >>= 1) { sm += __shfl_xor(sm, o); ss += __shfl_xor(ss, o); }
    float m = sm * (1.f / 512.f);
    float inv = rsqrtf(ss * (1.f / 512.f) - m * m + EPSF);
#pragma unroll
    for (int j = 0; j < 8; j++) {
      int col = lane + j * 64;
      float nv = (vals[j] - m) * inv * g[col] + beta[col];
      pbf[(col >> 4) * 264 + r * 16 + (col & 15)] = f2bf_s(nv);
    }
  }
  __syncthreads();

  // ---- dw 3x3 s2 (+folded BN) x3 -> t3[iw][pos][c] ----
  {
    int c = tid511 & 31, oy = (tid511 >> 5) & 7, oxh = tid511 >> 8;
    int base = oxh * 8 - 1;
    float ra[9], rb[9], rc[9];
    int iy0 = 2 * oy - 1;
#pragma unroll
    for (int k = 0; k < 9; k++) {
      int ic = base + k;
      bool cv = (ic >= 0);
      ra[k] = (cv && iy0 >= 0) ? bf2f(pbf[c * 264 + iy0 * 16 + ic]) : 0.f;
      rb[k] = cv ? bf2f(pbf[c * 264 + (2 * oy) * 16 + ic]) : 0.f;
      rc[k] = cv ? bf2f(pbf[c * 264 + (2 * oy + 1) * 16 + ic]) : 0.f;
    }
    for (int iw = 0; iw < 3; iw++) {
      const float* w9 = qkvdw + iw * 288;
      float w00 = w9[0 * 32 + c], w01 = w9[1 * 32 + c], w02 = w9[2 * 32 + c];
      float w10 = w9[3 * 32 + c], w11 = w9[4 * 32 + c], w12 = w9[5 * 32 + c];
      float w20 = w9[6 * 32 + c], w21 = w9[7 * 32 + c], w22 = w9[8 * 32 + c];
      float shift = qkvdb[iw * 32 + c];
#pragma unroll
      for (int j = 0; j < 4; j++) {
        int ox = oxh * 4 + j;
        float acc = w00 * ra[2 * j] + w01 * ra[2 * j + 1] + w02 * ra[2 * j + 2]
                  + w10 * rb[2 * j] + w11 * rb[2 * j + 1] + w12 * rb[2 * j + 2]
                  + w20 * rc[2 * j] + w21 * rc[2 * j + 1] + w22 * rc[2 * j + 2];
        t3s[(iw * 64 + oy * 8 + ox) * 40 + c] = f2bf_s(acc + shift);
      }
    }
  }
  __syncthreads();

  // ---- pw MFMA (one 16x16 tile per wave per iw) -> qe, ke, vt ----
  {
    int mi = mi_pw, ni = w8 >> 1;                 // ni 0..3
    for (int iw = 0; iw < 3; iw++) {
      short8v bb = *(const short8v*)&t3s[(iw * 64 + ni * 16 + row) * 40 + kg * 8];
      f32x4 z = {};
      f32x4 acc = __builtin_amdgcn_mfma_f32_16x16x32_bf16(aq[iw], bb, z, 0, 0, 0);
      if (iw < 2) {
        short* tgt = (iw == 0) ? qe : ke;
#pragma unroll
        for (int r = 0; r < 4; r++) {
          int d = mi * 16 + kg * 4 + r;
          tgt[d * 72 + ni * 16 + row] = f2bf_s(acc[r]);
        }
      } else {
        int e = ni * 16 + row;
        int fb = mi * 16 + kg * 4;
        short4v v0;
        v0.x = f2bf_s(acc[0]); v0.y = f2bf_s(acc[1]);
        v0.z = f2bf_s(acc[2]); v0.w = f2bf_s(acc[3]);
        *(short4v*)&vt[e * 40 + fb] = v0;
      }
    }
  }
  __syncthreads();

  // ---- QK^T (waves 0-3 of each half) + position -> sc fp32 ----
  if (w8 < 4) {
    int mi = w8 & 1, ni = (w8 >> 1) & 1;
    f32x4 acc = {};
#pragma unroll
    for (int kk = 0; kk < 2; kk++) {
      short8v a = *(const short8v*)&qe[(mi * 16 + row) * 72 + kk * 32 + kg * 8];
      short8v bb = *(const short8v*)&ke[(ni * 16 + row) * 72 + kk * 32 + kg * 8];
      acc = __builtin_amdgcn_mfma_f32_16x16x32_bf16(a, bb, acc, 0, 0, 0);
    }
#pragma unroll
    for (int r = 0; r < 4; r++) {
      int d = mi * 16 + kg * 4 + r, f = ni * 16 + row;
      sc[d * 33 + f] = acc[r] * 0.125f + posn[d * 32 + f];
    }
  }
  __syncthreads();

  // ---- softmax (first 256 threads of each half) ----
  if (tid511 < 256) {
    int srow = tid511 >> 3, sg = tid511 & 7;
    float v0 = sc[srow * 33 + sg * 4 + 0];
    float v1 = sc[srow * 33 + sg * 4 + 1];
    float v2 = sc[srow * 33 + sg * 4 + 2];
    float v3 = sc[srow * 33 + sg * 4 + 3];
    float mx = fmaxf(fmaxf(v0, v1), fmaxf(v2, v3));
    mx = fmaxf(mx, __shfl_xor(mx, 1));
    mx = fmaxf(mx, __shfl_xor(mx, 2));
    mx = fmaxf(mx, __shfl_xor(mx, 4));
    float e0 = __expf(v0 - mx), e1 = __expf(v1 - mx);
    float e2 = __expf(v2 - mx), e3 = __expf(v3 - mx);
    float sum = e0 + e1 + e2 + e3;
    sum += __shfl_xor(sum, 1); sum += __shfl_xor(sum, 2); sum += __shfl_xor(sum, 4);
    float inv = 1.f / sum;
    short4v pk;
    pk.x = f2bf_s(e0 * inv); pk.y = f2bf_s(e1 * inv);
    pk.z = f2bf_s(e2 * inv); pk.w = f2bf_s(e3 * inv);
    *(short4v*)&pa[srow * 40 + sg * 4] = pk;
  }
  __syncthreads();

  // ---- PV (one tile per wave) -> ore[p1][d*8+p2] ----
  {
    int mi = w8 & 1, et = w8 >> 1;
    short8v a = *(const short8v*)&pa[(mi * 16 + row) * 40 + kg * 8];
    int e = et * 16 + row;
    short8v bb = *(const short8v*)&vt[e * 40 + kg * 8];
    f32x4 z = {};
    f32x4 acc = __builtin_amdgcn_mfma_f32_16x16x32_bf16(a, bb, z, 0, 0, 0);
#pragma unroll
    for (int r = 0; r < 4; r++) {
      int d = mi * 16 + kg * 4 + r;
      ore[(e >> 3) * 264 + d * 8 + (e & 7)] = f2bf_s(acc[r]);
    }
  }
  __syncthreads();

  // ---- c1d: thread = (n, uh) within half ----
  {
    int n = tid511 & 255, uh = tid511 >> 8;
    float o8[8];
#pragma unroll
    for (int c = 0; c < 8; c++) o8[c] = bf2f(ore[c * 264 + n]);
#pragma unroll
    for (int uu = 0; uu < 8; uu++) {
      int u = uh * 8 + uu;
      float acc = c1b[u];
#pragma unroll
      for (int c = 0; c < 8; c++) acc += c1w[u * 8 + c] * o8[c];
      xc1[u * 264 + n] = f2bf_s(acc);
    }
  }
  __syncthreads();

  // ---- lin MFMA (4 tiles per wave; halves share linb stream) + residual ----
  {
    short8v a8[8];
#pragma unroll
    for (int kk = 0; kk < 8; kk++)
      a8[kk] = *(const short8v*)&xc1[row * 264 + kk * 32 + kg * 8];
#pragma unroll
    for (int t = 0; t < 4; t++) {
      int nt = w8 * 4 + t;
      const short* bb_base = linb + (nt * 16 + row) * 256 + kg * 8;
      f32x4 acc = {};
#pragma unroll
      for (int kk = 0; kk < 8; kk++) {
        short8v bb = *(const short8v*)(bb_base + kk * 32);
        acc = __builtin_amdgcn_mfma_f32_16x16x32_bf16(a8[kk], bb, acc, 0, 0, 0);
      }
      int m = nt * 16 + row;
      float lb = lin_b[m];
#pragma unroll
      for (int r = 0; r < 4; r++) {
        int u = kg * 4 + r;
        xo[u * 512 + m] = xr[t][r] + acc[r] + lb;
      }
    }
  }
}

// ---------------- K_FFN4: 1024 threads, staged weights, vector conv ----------
__global__ __launch_bounds__(1024, 4) void k_ffn4(
    const float* __restrict__ x, const float* __restrict__ g,
    const float* __restrict__ beta, const short* __restrict__ f1wg,
    const float* __restrict__ f1b, const float* __restrict__ convW,
    const float* __restrict__ convB, const short* __restrict__ img,
    const float* __restrict__ pwbias, const float* __restrict__ f2b,
    float* __restrict__ xg) {
  __shared__ __align__(16) char smem[149504];
  short* p_lds = (short*)smem;                 // [256][40]
  short* f1w_lds = (short*)(smem + 20480);     // [128][40]
  short* sT = (short*)smem;                    // [256][152]
  short* sY = (short*)(smem + 77824);          // [128][280]
  short* pw_lds = (short*)(smem + 77824);      // [128][152]
  short* f2w_lds = (short*)(smem + 77824 + 38912);

  int b = blockIdx.x, tid = threadIdx.x;
  int lane = tid & 63, wid = tid >> 6;         // wid 0..15
  int row = lane & 15, kg = lane >> 4;
  const float* xb = x + (size_t)b * 8192;
  float* xo = xg + (size_t)b * 8192;

  // ---- prefetch pw/f2 weight image into regs ----
  const uint4* imgu = (const uint4*)img;
  uint4 pf0 = imgu[tid], pf1 = imgu[tid + 1024];
  uint4 pf2 = {};
  if (tid < 992) pf2 = imgu[tid + 2048];

  // ---- prefetch conv weights + all biases (hide L2 latency) ----
  int cch = tid & 127;
  float w_[9];
#pragma unroll
  for (int k = 0; k < 9; k++) w_[k] = convW[k * 128 + cch];
  float cb = convB[cch];
  int o0 = (wid & 3) * 32;
  float f1bv[8], pwbv[8], f2bv[8];
#pragma unroll
  for (int j = 0; j < 4; j++) {
    f1bv[j]     = f1b[o0 + kg * 4 + j];
    f1bv[4 + j] = f1b[o0 + 16 + kg * 4 + j];
    pwbv[j]     = pwbias[o0 + kg * 4 + j];
    pwbv[4 + j] = pwbias[o0 + 16 + kg * 4 + j];
    f2bv[j]     = f2b[kg * 4 + j];
    f2bv[4 + j] = f2b[16 + kg * 4 + j];
  }

  // ---- early residual loads (T14): matches f2 store pattern ----
  float xr[2][4];
#pragma unroll
  for (int mi = 0; mi < 2; mi++)
#pragma unroll
    for (int r2 = 0; r2 < 4; r2++)
      xr[mi][r2] = xo[wid * 512 + mi * 256 + kg * 64 + r2 * 16 + row];

  // ---- stage f1w ----
  if (tid < 640) ((uint4*)f1w_lds)[tid] = ((const uint4*)f1wg)[tid];

  // ---- LN2 + patches -> p_lds [pos][40] bf16 (one row per wave) ----
  {
    int r = wid;
    float vals[8];
    float s = 0.f, ss = 0.f;
#pragma unroll
    for (int j = 0; j < 8; j++) {
      float t = xb[r * 512 + lane + j * 64];
      vals[j] = t; s += t; ss += t * t;
    }
#pragma unroll
    for (int o = 32; o; o >>= 1) { s += __shfl_xor(s, o); ss += __shfl_xor(ss, o); }
    float m = s * (1.f / 512.f);
    float inv = rsqrtf(ss * (1.f / 512.f) - m * m + EPSF);
#pragma unroll
    for (int j = 0; j < 8; j++) {
      int col = lane + j * 64;
      float nv = (vals[j] - m) * inv * g[col] + beta[col];
      p_lds[(r * 16 + (col & 15)) * 40 + (col >> 4)] = f2bf_s(nv);
    }
  }
  __syncthreads();

  // ---- f1 MFMA: y1[o=128][pos=256], K=32; wave tile 32x64 ----
  {
    int pos0 = (wid >> 2) * 64;
    short8v a0 = *(const short8v*)&f1w_lds[(o0 + row) * 40 + kg * 8];
    short8v a1 = *(const short8v*)&f1w_lds[(o0 + 16 + row) * 40 + kg * 8];
#pragma unroll
    for (int ni = 0; ni < 4; ni++) {
      short8v bb = *(const short8v*)&p_lds[(pos0 + ni * 16 + row) * 40 + kg * 8];
      f32x4 z = {};
      f32x4 c0 = __builtin_amdgcn_mfma_f32_16x16x32_bf16(a0, bb, z, 0, 0, 0);
      f32x4 c1 = __builtin_amdgcn_mfma_f32_16x16x32_bf16(a1, bb, z, 0, 0, 0);
      int pos = pos0 + ni * 16 + row;
#pragma unroll
      for (int r2 = 0; r2 < 4; r2++) {
        int c = o0 + kg * 4 + r2;
        sY[c * 280 + pos] = f2bf_s(fmaxf(c0[r2] + f1bv[r2], 0.f));
        sY[(c + 16) * 280 + pos] = f2bf_s(fmaxf(c1[r2] + f1bv[4 + r2], 0.f));
      }
    }
  }
  __syncthreads();

  // ---- depthwise 3x3 s1 (+folded BN) -> sT [pos][152] bf16 ----
  {
    int c = cch, strip = tid >> 7;             // 2 rows per thread
#pragma unroll
    for (int j = 0; j < 2; j++) {
      int h = strip * 2 + j;
      float acc[16];
#pragma unroll
      for (int w = 0; w < 16; w++) acc[w] = cb;
#pragma unroll
      for (int rr = 0; rr < 3; rr++) {
        int rg = h - 1 + rr;
        if (rg < 0 || rg > 15) continue;
        short8v s0 = *(const short8v*)&sY[c * 280 + rg * 16];
        short8v s1 = *(const short8v*)&sY[c * 280 + rg * 16 + 8];
        float f[18];
        f[0] = 0.f; f[17] = 0.f;
#pragma unroll
        for (int i = 0; i < 8; i++) { f[1 + i] = bf2f(s0[i]); f[9 + i] = bf2f(s1[i]); }
        float w0 = w_[rr * 3], w1 = w_[rr * 3 + 1], w2 = w_[rr * 3 + 2];
#pragma unroll
        for (int w = 0; w < 16; w++)
          acc[w] += w0 * f[w] + w1 * f[w + 1] + w2 * f[w + 2];
      }
#pragma unroll
      for (int w = 0; w < 16; w++)
        sT[(h * 16 + w) * 152 + c] = f2bf_s(acc[w]);
    }
  }
  __syncthreads();

  // ---- drop prefetched weights into sY region ----
  {
    uint4* wdst = (uint4*)pw_lds;
    wdst[tid] = pf0; wdst[tid + 1024] = pf1;
    if (tid < 992) wdst[tid + 2048] = pf2;
  }
  __syncthreads();

  // ---- fpw MFMA: r[o=128][pos=256], K=128; wave tile 32x64 ----
  int pos0 = (wid >> 2) * 64;
  f32x4 facc[2][4] = {};
#pragma unroll
  for (int kk = 0; kk < 4; kk++) {
    int k0 = kk * 32 + kg * 8;
    short8v a0 = *(const short8v*)&pw_lds[(o0 + row) * 152 + k0];
    short8v a1 = *(const short8v*)&pw_lds[(o0 + 16 + row) * 152 + k0];
    short8v bb[4];
#pragma unroll
    for (int ni = 0; ni < 4; ni++)
      bb[ni] = *(const short8v*)&sT[(pos0 + ni * 16 + row) * 152 + k0];
#pragma unroll
    for (int ni = 0; ni < 4; ni++) {
      facc[0][ni] = __builtin_amdgcn_mfma_f32_16x16x32_bf16(a0, bb[ni], facc[0][ni], 0, 0, 0);
      facc[1][ni] = __builtin_amdgcn_mfma_f32_16x16x32_bf16(a1, bb[ni], facc[1][ni], 0, 0, 0);
    }
  }
  __syncthreads();

  // ---- bias + ReLU -> sT[pos][o] (overwrite) ----
#pragma unroll
  for (int mi = 0; mi < 2; mi++) {
    int ob = o0 + mi * 16 + kg * 4;
#pragma unroll
    for (int ni = 0; ni < 4; ni++) {
      int pos = pos0 + ni * 16 + row;
      short4v pk;
      pk.x = f2bf_s(fmaxf(facc[mi][ni][0] + pwbv[mi * 4 + 0], 0.f));
      pk.y = f2bf_s(fmaxf(facc[mi][ni][1] + pwbv[mi * 4 + 1], 0.f));
      pk.z = f2bf_s(fmaxf(facc[mi][ni][2] + pwbv[mi * 4 + 2], 0.f));
      pk.w = f2bf_s(fmaxf(facc[mi][ni][3] + pwbv[mi * 4 + 3], 0.f));
      *(short4v*)&sT[pos * 152 + ob] = pk;
    }
  }
  __syncthreads();

  // ---- f2 MFMA: out[d=32][pos=256], K=128; direct residual store ----
  {
    f32x4 acc2[2] = {};
    int pos = wid * 16 + row;
#pragma unroll
    for (int kk = 0; kk < 4; kk++) {
      int k0 = kk * 32 + kg * 8;
      short8v a0 = *(const short8v*)&f2w_lds[row * 152 + k0];
      short8v a1 = *(const short8v*)&f2w_lds[(16 + row) * 152 + k0];
      short8v bb = *(const short8v*)&sT[pos * 152 + k0];
      acc2[0] = __builtin_amdgcn_mfma_f32_16x16x32_bf16(a0, bb, acc2[0], 0, 0, 0);
      acc2[1] = __builtin_amdgcn_mfma_f32_16x16x32_bf16(a1, bb, acc2[1], 0, 0, 0);
    }
#pragma unroll
    for (int mi = 0; mi < 2; mi++)
#pragma unroll
      for (int r2 = 0; r2 < 4; r2++) {
        xo[wid * 512 + mi * 256 + kg * 64 + r2 * 16 + row] =
            xr[mi][r2] + acc2[mi][r2] + f2bv[mi * 4 + r2];
      }
  }
}

extern "C" void kernel_launch(void* const* d_in, const int* in_sizes, int n_in,
                              void* d_out, int out_size, void* d_ws, size_t ws_size,
                              hipStream_t stream) {
  const float* x_in   = (const float*)d_in[0];
  const float* ln1_g  = (const float*)d_in[1];
  const float* ln1_b  = (const float*)d_in[2];
  const float* ln2_g  = (const float*)d_in[3];
  const float* ln2_b  = (const float*)d_in[4];
  const float* qkv_dw = (const float*)d_in[5];
  const float* qkv_bng = (const float*)d_in[6];
  const float* qkv_bnb = (const float*)d_in[7];
  const float* qkv_bnm = (const float*)d_in[8];
  const float* qkv_bnv = (const float*)d_in[9];
  const float* qkv_pw = (const float*)d_in[10];
  const float* position = (const float*)d_in[11];
  const float* c1d_w  = (const float*)d_in[12];
  const float* c1d_b  = (const float*)d_in[13];
  const float* lin_w  = (const float*)d_in[14];
  const float* lin_b  = (const float*)d_in[15];
  const float* f1_w   = (const float*)d_in[16];
  const float* f1_b   = (const float*)d_in[17];
  const float* fdw_w  = (const float*)d_in[18];
  const float* fdw_b  = (const float*)d_in[19];
  const float* f_bng  = (const float*)d_in[20];
  const float* f_bnb  = (const float*)d_in[21];
  const float* f_bnm  = (const float*)d_in[22];
  const float* f_bnv  = (const float*)d_in[23];
  const float* fpw_w  = (const float*)d_in[24];
  const float* fpw_b  = (const float*)d_in[25];
  const float* f2_w   = (const float*)d_in[26];
  const float* f2_b   = (const float*)d_in[27];

  float* xbuf = (float*)d_out;                 // running x lives in d_out
  short* qkvA = (short*)d_ws;                  // 7680
  short* linb = qkvA + 7680;                   // 262144
  short* f1wb = linb + 262144;                 // 10240
  short* img  = f1wb + 10240;                  // 48640
  float* convW = (float*)(img + 48640);        // 2304
  float* convB = convW + 2304;                 // 256
  float* qkvdw = convB + 256;                  // 1728
  float* qkvdb = qkvdw + 1728;                 // 192

  k_prep<<<1024, 256, 0, stream>>>(f1_w, fpw_w, f2_w, qkv_pw, lin_w,
      fdw_w, fdw_b, f_bng, f_bnb, f_bnm, f_bnv,
      qkv_dw, qkv_bng, qkv_bnb, qkv_bnm, qkv_bnv,
      qkvA, linb, f1wb, img, convW, convB, qkvdw, qkvdb);
  for (int l = 0; l < 2; l++) {
    const float* xin = (l == 0) ? x_in : xbuf;
    k_att2<<<B_ / 2, 1024, 0, stream>>>(xin, ln1_g + l * 512, ln1_b + l * 512,
        qkvdw + l * 864, qkvdb + l * 96, qkvA + l * 3840,
        position + l * 1024, c1d_w + l * 128, c1d_b + l * 16,
        linb + l * 131072, lin_b + l * 512, xbuf);
    k_ffn4<<<B_, 1024, 0, stream>>>(xbuf, ln2_g + l * 512, ln2_b + l * 512,
        f1wb + l * 5120, f1_b + l * 128, convW + l * 1152, convB + l * 128,
        img + l * 24320, fpw_b + l * 128, f2_b + l * 32, xbuf);
  }
}

// Round 12
// 406.116 us; speedup vs baseline: 1.0100x; 1.0100x over previous
//
#include <hip/hip_runtime.h>
#include <hip/hip_bf16.h>

#define B_ 2048
#define EPSF 1e-5f

typedef __attribute__((ext_vector_type(8))) short short8v;
typedef __attribute__((ext_vector_type(4))) short short4v;
typedef __attribute__((ext_vector_type(4))) float f32x4;

// float -> bf16 bits via compiler-native conversion
__device__ __forceinline__ short f2bf_s(float f) {
  __hip_bfloat16 h = __float2bfloat16(f);
  return *reinterpret_cast<const short*>(&h);
}
__device__ __forceinline__ float bf2f(short s) {
  return __uint_as_float(((unsigned)(unsigned short)s) << 16);
}

// ---------------- weight prep -------------------------------------------------
__global__ __launch_bounds__(256) void k_prep(
    const float* __restrict__ f1_w, const float* __restrict__ fpw_w,
    const float* __restrict__ f2_w, const float* __restrict__ qkv_pw,
    const float* __restrict__ lin_w, const float* __restrict__ fdw_w,
    const float* __restrict__ fdw_b, const float* __restrict__ f_bng,
    const float* __restrict__ f_bnb, const float* __restrict__ f_bnm,
    const float* __restrict__ f_bnv, const float* __restrict__ qkv_dw,
    const float* __restrict__ qkv_bng, const float* __restrict__ qkv_bnb,
    const float* __restrict__ qkv_bnm, const float* __restrict__ qkv_bnv,
    short* __restrict__ qkvA, short* __restrict__ linb,
    short* __restrict__ f1wb, short* __restrict__ img,
    float* __restrict__ convW, float* __restrict__ convB,
    float* __restrict__ qkvdw, float* __restrict__ qkvdb) {
  int i = blockIdx.x * 256 + threadIdx.x;
  if (i < 7680) {
    int l = i / 3840, r = i % 3840;
    int io = r / 40, c = r % 40;
    qkvA[i] = (c < 32) ? f2bf_s(qkv_pw[l * 3072 + io * 32 + c]) : (short)0;
  }
  if (i < 262144) linb[i] = f2bf_s(lin_w[i]);
  if (i < 10240) {
    int l = i / 5120, r = i % 5120, o = r / 40, kk = r % 40;
    f1wb[i] = (kk < 32) ? f2bf_s(f1_w[l * 4096 + o * 32 + kk]) : (short)0;
  }
  if (i < 48640) {
    int l = i / 24320, r = i % 24320;
    short val;
    if (r < 19456) {
      int o = r / 152, kk = r % 152;
      val = (kk < 128) ? f2bf_s(fpw_w[l * 16384 + o * 128 + kk]) : (short)0;
    } else {
      int r2 = r - 19456;
      int d = r2 / 152, kk = r2 % 152;
      val = (kk < 128) ? f2bf_s(f2_w[l * 4096 + d * 128 + kk]) : (short)0;
    }
    img[i] = val;
  }
  if (i < 256) {
    int l = i >> 7, c = i & 127;
    float scale = f_bng[l * 128 + c] * rsqrtf(f_bnv[l * 128 + c] + EPSF);
#pragma unroll
    for (int k = 0; k < 9; k++)
      convW[l * 1152 + k * 128 + c] = fdw_w[(l * 128 + c) * 9 + k] * scale;
    convB[l * 128 + c] =
        (fdw_b[l * 128 + c] - f_bnm[l * 128 + c]) * scale + f_bnb[l * 128 + c];
  }
  if (i < 192) {  // qkv conv BN fold: [l][3][9][32] + [l][3][32]
    int l = i / 96, iw = (i % 96) / 32, c = i % 32;
    int bi = l * 96 + iw * 32 + c;
    float scale = qkv_bng[bi] * rsqrtf(qkv_bnv[bi] + EPSF);
#pragma unroll
    for (int k = 0; k < 9; k++)
      qkvdw[((l * 3 + iw) * 9 + k) * 32 + c] =
          qkv_dw[(l * 96 + iw * 32 + c) * 9 + k] * scale;
    qkvdb[bi] = qkv_bnb[bi] - qkv_bnm[bi] * scale;
  }
}

// ---------------- K_ATT3: 1 sample/block, 512 threads, LDS 46592 -> 3/CU -----
// LDS overlay:
//   pbf  [32][264] bf16 @0      (16896)   -- LN1 patches; overlays after conv:
//       sc fp32 [32][33] @0     (4224)
//       pa  [32][40]  @4224     (2560)
//       ore [8][264]  @6784     (4224)
//   t3s [3][64][40] @16896      (15360)   -- overlay: xc1 [16][264] @16896
//   qe  [32][72]  @32256        (4608)
//   ke  [32][72]  @36864        (4608)
//   vt  [64][40]  @41472        (5120)
__global__ __launch_bounds__(512, 6) void k_att3(
    const float* __restrict__ xin, const float* __restrict__ g,
    const float* __restrict__ beta, const float* __restrict__ qkvdw,
    const float* __restrict__ qkvdb, const short* __restrict__ qkvA,
    const float* __restrict__ posn, const float* __restrict__ c1w,
    const float* __restrict__ c1b, const short* __restrict__ linb,
    const float* __restrict__ lin_b, float* __restrict__ xout) {
  __shared__ __align__(16) char smem[46592];
  int tid = threadIdx.x;
  int lane = tid & 63, w8 = tid >> 6;           // 8 waves
  int row = lane & 15, kg = lane >> 4;

  float* sc  = (float*)smem;
  short* pbf = (short*)smem;
  short* pa  = (short*)(smem + 4224);
  short* ore = (short*)(smem + 6784);
  short* t3s = (short*)(smem + 16896);
  short* xc1 = (short*)(smem + 16896);
  short* qe  = (short*)(smem + 32256);
  short* ke  = (short*)(smem + 36864);
  short* vt  = (short*)(smem + 41472);

  int b = blockIdx.x;
  const float* xb = xin + (size_t)b * 8192;
  float* xo = xout + (size_t)b * 8192;

  // ---- early prefetches ----
  float xr[4][4];
#pragma unroll
  for (int t = 0; t < 4; t++)
#pragma unroll
    for (int r = 0; r < 4; r++)
      xr[t][r] = xb[(kg * 4 + r) * 512 + (w8 * 4 + t) * 16 + row];
  int mi_pw = w8 & 1;
  short8v aq[3];
#pragma unroll
  for (int iw = 0; iw < 3; iw++)
    aq[iw] = *(const short8v*)&qkvA[(iw * 32 + mi_pw * 16 + row) * 40 + kg * 8];

  // ---- LN1 + to_patches -> pbf bf16 (2 rows per wave) ----
  for (int r = w8; r < 16; r += 8) {
    float vals[8];
    float sm = 0.f, ss = 0.f;
#pragma unroll
    for (int j = 0; j < 8; j++) {
      float t = xb[r * 512 + lane + j * 64];
      vals[j] = t; sm += t; ss += t * t;
    }
#pragma unroll
    for (int o = 32; o; o >>= 1) { sm += __shfl_xor(sm, o); ss += __shfl_xor(ss, o); }
    float m = sm * (1.f / 512.f);
    float inv = rsqrtf(ss * (1.f / 512.f) - m * m + EPSF);
#pragma unroll
    for (int j = 0; j < 8; j++) {
      int col = lane + j * 64;
      float nv = (vals[j] - m) * inv * g[col] + beta[col];
      pbf[(col >> 4) * 264 + r * 16 + (col & 15)] = f2bf_s(nv);
    }
  }
  __syncthreads();

  // ---- dw 3x3 s2 (+folded BN) x3 -> t3[iw][pos][c] ----
  {
    int c = tid & 31, oy = (tid >> 5) & 7, oxh = tid >> 8;
    int base = oxh * 8 - 1;
    float ra[9], rb[9], rc[9];
    int iy0 = 2 * oy - 1;
#pragma unroll
    for (int k = 0; k < 9; k++) {
      int ic = base + k;
      bool cv = (ic >= 0);
      ra[k] = (cv && iy0 >= 0) ? bf2f(pbf[c * 264 + iy0 * 16 + ic]) : 0.f;
      rb[k] = cv ? bf2f(pbf[c * 264 + (2 * oy) * 16 + ic]) : 0.f;
      rc[k] = cv ? bf2f(pbf[c * 264 + (2 * oy + 1) * 16 + ic]) : 0.f;
    }
    for (int iw = 0; iw < 3; iw++) {
      const float* w9 = qkvdw + iw * 288;
      float w00 = w9[0 * 32 + c], w01 = w9[1 * 32 + c], w02 = w9[2 * 32 + c];
      float w10 = w9[3 * 32 + c], w11 = w9[4 * 32 + c], w12 = w9[5 * 32 + c];
      float w20 = w9[6 * 32 + c], w21 = w9[7 * 32 + c], w22 = w9[8 * 32 + c];
      float shift = qkvdb[iw * 32 + c];
#pragma unroll
      for (int j = 0; j < 4; j++) {
        int ox = oxh * 4 + j;
        float acc = w00 * ra[2 * j] + w01 * ra[2 * j + 1] + w02 * ra[2 * j + 2]
                  + w10 * rb[2 * j] + w11 * rb[2 * j + 1] + w12 * rb[2 * j + 2]
                  + w20 * rc[2 * j] + w21 * rc[2 * j + 1] + w22 * rc[2 * j + 2];
        t3s[(iw * 64 + oy * 8 + ox) * 40 + c] = f2bf_s(acc + shift);
      }
    }
  }
  __syncthreads();

  // ---- pw MFMA (one 16x16 tile per wave per iw) -> qe, ke, vt ----
  {
    int mi = mi_pw, ni = w8 >> 1;                 // ni 0..3
    for (int iw = 0; iw < 3; iw++) {
      short8v bb = *(const short8v*)&t3s[(iw * 64 + ni * 16 + row) * 40 + kg * 8];
      f32x4 z = {};
      f32x4 acc = __builtin_amdgcn_mfma_f32_16x16x32_bf16(aq[iw], bb, z, 0, 0, 0);
      if (iw < 2) {
        short* tgt = (iw == 0) ? qe : ke;
#pragma unroll
        for (int r = 0; r < 4; r++) {
          int d = mi * 16 + kg * 4 + r;
          tgt[d * 72 + ni * 16 + row] = f2bf_s(acc[r]);
        }
      } else {
        int e = ni * 16 + row;
        int fb = mi * 16 + kg * 4;
        short4v v0;
        v0.x = f2bf_s(acc[0]); v0.y = f2bf_s(acc[1]);
        v0.z = f2bf_s(acc[2]); v0.w = f2bf_s(acc[3]);
        *(short4v*)&vt[e * 40 + fb] = v0;
      }
    }
  }
  __syncthreads();

  // ---- QK^T (waves 0-3) + position -> sc fp32 ----
  if (w8 < 4) {
    int mi = w8 & 1, ni = (w8 >> 1) & 1;
    f32x4 acc = {};
#pragma unroll
    for (int kk = 0; kk < 2; kk++) {
      short8v a = *(const short8v*)&qe[(mi * 16 + row) * 72 + kk * 32 + kg * 8];
      short8v bb = *(const short8v*)&ke[(ni * 16 + row) * 72 + kk * 32 + kg * 8];
      acc = __builtin_amdgcn_mfma_f32_16x16x32_bf16(a, bb, acc, 0, 0, 0);
    }
#pragma unroll
    for (int r = 0; r < 4; r++) {
      int d = mi * 16 + kg * 4 + r, f = ni * 16 + row;
      sc[d * 33 + f] = acc[r] * 0.125f + posn[d * 32 + f];
    }
  }
  __syncthreads();

  // ---- softmax (first 256 threads) ----
  if (tid < 256) {
    int srow = tid >> 3, sg = tid & 7;
    float v0 = sc[srow * 33 + sg * 4 + 0];
    float v1 = sc[srow * 33 + sg * 4 + 1];
    float v2 = sc[srow * 33 + sg * 4 + 2];
    float v3 = sc[srow * 33 + sg * 4 + 3];
    float mx = fmaxf(fmaxf(v0, v1), fmaxf(v2, v3));
    mx = fmaxf(mx, __shfl_xor(mx, 1));
    mx = fmaxf(mx, __shfl_xor(mx, 2));
    mx = fmaxf(mx, __shfl_xor(mx, 4));
    float e0 = __expf(v0 - mx), e1 = __expf(v1 - mx);
    float e2 = __expf(v2 - mx), e3 = __expf(v3 - mx);
    float sum = e0 + e1 + e2 + e3;
    sum += __shfl_xor(sum, 1); sum += __shfl_xor(sum, 2); sum += __shfl_xor(sum, 4);
    float inv = 1.f / sum;
    short4v pk;
    pk.x = f2bf_s(e0 * inv); pk.y = f2bf_s(e1 * inv);
    pk.z = f2bf_s(e2 * inv); pk.w = f2bf_s(e3 * inv);
    *(short4v*)&pa[srow * 40 + sg * 4] = pk;
  }
  __syncthreads();

  // ---- PV (one tile per wave) -> ore[p1][d*8+p2] ----
  {
    int mi = w8 & 1, et = w8 >> 1;
    short8v a = *(const short8v*)&pa[(mi * 16 + row) * 40 + kg * 8];
    int e = et * 16 + row;
    short8v bb = *(const short8v*)&vt[e * 40 + kg * 8];
    f32x4 z = {};
    f32x4 acc = __builtin_amdgcn_mfma_f32_16x16x32_bf16(a, bb, z, 0, 0, 0);
#pragma unroll
    for (int r = 0; r < 4; r++) {
      int d = mi * 16 + kg * 4 + r;
      ore[(e >> 3) * 264 + d * 8 + (e & 7)] = f2bf_s(acc[r]);
    }
  }
  __syncthreads();

  // ---- c1d: thread = (n, uh) ----
  {
    int n = tid & 255, uh = tid >> 8;
    float o8[8];
#pragma unroll
    for (int c = 0; c < 8; c++) o8[c] = bf2f(ore[c * 264 + n]);
#pragma unroll
    for (int uu = 0; uu < 8; uu++) {
      int u = uh * 8 + uu;
      float acc = c1b[u];
#pragma unroll
      for (int c = 0; c < 8; c++) acc += c1w[u * 8 + c] * o8[c];
      xc1[u * 264 + n] = f2bf_s(acc);
    }
  }
  __syncthreads();

  // ---- lin MFMA (4 tiles per wave) + bias + residual ----
  {
    short8v a8[8];
#pragma unroll
    for (int kk = 0; kk < 8; kk++)
      a8[kk] = *(const short8v*)&xc1[row * 264 + kk * 32 + kg * 8];
#pragma unroll
    for (int t = 0; t < 4; t++) {
      int nt = w8 * 4 + t;
      const short* bb_base = linb + (nt * 16 + row) * 256 + kg * 8;
      f32x4 acc = {};
#pragma unroll
      for (int kk = 0; kk < 8; kk++) {
        short8v bb = *(const short8v*)(bb_base + kk * 32);
        acc = __builtin_amdgcn_mfma_f32_16x16x32_bf16(a8[kk], bb, acc, 0, 0, 0);
      }
      int m = nt * 16 + row;
      float lb = lin_b[m];
#pragma unroll
      for (int r = 0; r < 4; r++) {
        int u = kg * 4 + r;
        xo[u * 512 + m] = xr[t][r] + acc[r] + lb;
      }
    }
  }
}

// ---------------- K_FFN4: 1024 threads, staged weights, vector conv ----------
__global__ __launch_bounds__(1024, 4) void k_ffn4(
    const float* __restrict__ x, const float* __restrict__ g,
    const float* __restrict__ beta, const short* __restrict__ f1wg,
    const float* __restrict__ f1b, const float* __restrict__ convW,
    const float* __restrict__ convB, const short* __restrict__ img,
    const float* __restrict__ pwbias, const float* __restrict__ f2b,
    float* __restrict__ xg) {
  __shared__ __align__(16) char smem[149504];
  short* p_lds = (short*)smem;                 // [256][40]
  short* f1w_lds = (short*)(smem + 20480);     // [128][40]
  short* sT = (short*)smem;                    // [256][152]
  short* sY = (short*)(smem + 77824);          // [128][280]
  short* pw_lds = (short*)(smem + 77824);      // [128][152]
  short* f2w_lds = (short*)(smem + 77824 + 38912);

  int b = blockIdx.x, tid = threadIdx.x;
  int lane = tid & 63, wid = tid >> 6;         // wid 0..15
  int row = lane & 15, kg = lane >> 4;
  const float* xb = x + (size_t)b * 8192;
  float* xo = xg + (size_t)b * 8192;

  // ---- prefetch pw/f2 weight image into regs ----
  const uint4* imgu = (const uint4*)img;
  uint4 pf0 = imgu[tid], pf1 = imgu[tid + 1024];
  uint4 pf2 = {};
  if (tid < 992) pf2 = imgu[tid + 2048];

  // ---- prefetch conv weights + all biases (hide L2 latency) ----
  int cch = tid & 127;
  float w_[9];
#pragma unroll
  for (int k = 0; k < 9; k++) w_[k] = convW[k * 128 + cch];
  float cb = convB[cch];
  int o0 = (wid & 3) * 32;
  float f1bv[8], pwbv[8], f2bv[8];
#pragma unroll
  for (int j = 0; j < 4; j++) {
    f1bv[j]     = f1b[o0 + kg * 4 + j];
    f1bv[4 + j] = f1b[o0 + 16 + kg * 4 + j];
    pwbv[j]     = pwbias[o0 + kg * 4 + j];
    pwbv[4 + j] = pwbias[o0 + 16 + kg * 4 + j];
    f2bv[j]     = f2b[kg * 4 + j];
    f2bv[4 + j] = f2b[16 + kg * 4 + j];
  }

  // ---- early residual loads (T14): matches f2 store pattern ----
  float xr[2][4];
#pragma unroll
  for (int mi = 0; mi < 2; mi++)
#pragma unroll
    for (int r2 = 0; r2 < 4; r2++)
      xr[mi][r2] = xo[wid * 512 + mi * 256 + kg * 64 + r2 * 16 + row];

  // ---- stage f1w ----
  if (tid < 640) ((uint4*)f1w_lds)[tid] = ((const uint4*)f1wg)[tid];

  // ---- LN2 + patches -> p_lds [pos][40] bf16 (one row per wave) ----
  {
    int r = wid;
    float vals[8];
    float s = 0.f, ss = 0.f;
#pragma unroll
    for (int j = 0; j < 8; j++) {
      float t = xb[r * 512 + lane + j * 64];
      vals[j] = t; s += t; ss += t * t;
    }
#pragma unroll
    for (int o = 32; o; o >>= 1) { s += __shfl_xor(s, o); ss += __shfl_xor(ss, o); }
    float m = s * (1.f / 512.f);
    float inv = rsqrtf(ss * (1.f / 512.f) - m * m + EPSF);
#pragma unroll
    for (int j = 0; j < 8; j++) {
      int col = lane + j * 64;
      float nv = (vals[j] - m) * inv * g[col] + beta[col];
      p_lds[(r * 16 + (col & 15)) * 40 + (col >> 4)] = f2bf_s(nv);
    }
  }
  __syncthreads();

  // ---- f1 MFMA: y1[o=128][pos=256], K=32; wave tile 32x64 ----
  {
    int pos0 = (wid >> 2) * 64;
    short8v a0 = *(const short8v*)&f1w_lds[(o0 + row) * 40 + kg * 8];
    short8v a1 = *(const short8v*)&f1w_lds[(o0 + 16 + row) * 40 + kg * 8];
#pragma unroll
    for (int ni = 0; ni < 4; ni++) {
      short8v bb = *(const short8v*)&p_lds[(pos0 + ni * 16 + row) * 40 + kg * 8];
      f32x4 z = {};
      f32x4 c0 = __builtin_amdgcn_mfma_f32_16x16x32_bf16(a0, bb, z, 0, 0, 0);
      f32x4 c1 = __builtin_amdgcn_mfma_f32_16x16x32_bf16(a1, bb, z, 0, 0, 0);
      int pos = pos0 + ni * 16 + row;
#pragma unroll
      for (int r2 = 0; r2 < 4; r2++) {
        int c = o0 + kg * 4 + r2;
        sY[c * 280 + pos] = f2bf_s(fmaxf(c0[r2] + f1bv[r2], 0.f));
        sY[(c + 16) * 280 + pos] = f2bf_s(fmaxf(c1[r2] + f1bv[4 + r2], 0.f));
      }
    }
  }
  __syncthreads();

  // ---- depthwise 3x3 s1 (+folded BN) -> sT [pos][152] bf16 ----
  {
    int c = cch, strip = tid >> 7;             // 2 rows per thread
#pragma unroll
    for (int j = 0; j < 2; j++) {
      int h = strip * 2 + j;
      float acc[16];
#pragma unroll
      for (int w = 0; w < 16; w++) acc[w] = cb;
#pragma unroll
      for (int rr = 0; rr < 3; rr++) {
        int rg = h - 1 + rr;
        if (rg < 0 || rg > 15) continue;
        short8v s0 = *(const short8v*)&sY[c * 280 + rg * 16];
        short8v s1 = *(const short8v*)&sY[c * 280 + rg * 16 + 8];
        float f[18];
        f[0] = 0.f; f[17] = 0.f;
#pragma unroll
        for (int i = 0; i < 8; i++) { f[1 + i] = bf2f(s0[i]); f[9 + i] = bf2f(s1[i]); }
        float w0 = w_[rr * 3], w1 = w_[rr * 3 + 1], w2 = w_[rr * 3 + 2];
#pragma unroll
        for (int w = 0; w < 16; w++)
          acc[w] += w0 * f[w] + w1 * f[w + 1] + w2 * f[w + 2];
      }
#pragma unroll
      for (int w = 0; w < 16; w++)
        sT[(h * 16 + w) * 152 + c] = f2bf_s(acc[w]);
    }
  }
  __syncthreads();

  // ---- drop prefetched weights into sY region ----
  {
    uint4* wdst = (uint4*)pw_lds;
    wdst[tid] = pf0; wdst[tid + 1024] = pf1;
    if (tid < 992) wdst[tid + 2048] = pf2;
  }
  __syncthreads();

  // ---- fpw MFMA: r[o=128][pos=256], K=128; wave tile 32x64 ----
  int pos0 = (wid >> 2) * 64;
  f32x4 facc[2][4] = {};
#pragma unroll
  for (int kk = 0; kk < 4; kk++) {
    int k0 = kk * 32 + kg * 8;
    short8v a0 = *(const short8v*)&pw_lds[(o0 + row) * 152 + k0];
    short8v a1 = *(const short8v*)&pw_lds[(o0 + 16 + row) * 152 + k0];
    short8v bb[4];
#pragma unroll
    for (int ni = 0; ni < 4; ni++)
      bb[ni] = *(const short8v*)&sT[(pos0 + ni * 16 + row) * 152 + k0];
#pragma unroll
    for (int ni = 0; ni < 4; ni++) {
      facc[0][ni] = __builtin_amdgcn_mfma_f32_16x16x32_bf16(a0, bb[ni], facc[0][ni], 0, 0, 0);
      facc[1][ni] = __builtin_amdgcn_mfma_f32_16x16x32_bf16(a1, bb[ni], facc[1][ni], 0, 0, 0);
    }
  }
  __syncthreads();

  // ---- bias + ReLU -> sT[pos][o] (overwrite) ----
#pragma unroll
  for (int mi = 0; mi < 2; mi++) {
    int ob = o0 + mi * 16 + kg * 4;
#pragma unroll
    for (int ni = 0; ni < 4; ni++) {
      int pos = pos0 + ni * 16 + row;
      short4v pk;
      pk.x = f2bf_s(fmaxf(facc[mi][ni][0] + pwbv[mi * 4 + 0], 0.f));
      pk.y = f2bf_s(fmaxf(facc[mi][ni][1] + pwbv[mi * 4 + 1], 0.f));
      pk.z = f2bf_s(fmaxf(facc[mi][ni][2] + pwbv[mi * 4 + 2], 0.f));
      pk.w = f2bf_s(fmaxf(facc[mi][ni][3] + pwbv[mi * 4 + 3], 0.f));
      *(short4v*)&sT[pos * 152 + ob] = pk;
    }
  }
  __syncthreads();

  // ---- f2 MFMA: out[d=32][pos=256], K=128; direct residual store ----
  {
    f32x4 acc2[2] = {};
    int pos = wid * 16 + row;
#pragma unroll
    for (int kk = 0; kk < 4; kk++) {
      int k0 = kk * 32 + kg * 8;
      short8v a0 = *(const short8v*)&f2w_lds[row * 152 + k0];
      short8v a1 = *(const short8v*)&f2w_lds[(16 + row) * 152 + k0];
      short8v bb = *(const short8v*)&sT[pos * 152 + k0];
      acc2[0] = __builtin_amdgcn_mfma_f32_16x16x32_bf16(a0, bb, acc2[0], 0, 0, 0);
      acc2[1] = __builtin_amdgcn_mfma_f32_16x16x32_bf16(a1, bb, acc2[1], 0, 0, 0);
    }
#pragma unroll
    for (int mi = 0; mi < 2; mi++)
#pragma unroll
      for (int r2 = 0; r2 < 4; r2++) {
        xo[wid * 512 + mi * 256 + kg * 64 + r2 * 16 + row] =
            xr[mi][r2] + acc2[mi][r2] + f2bv[mi * 4 + r2];
      }
  }
}

extern "C" void kernel_launch(void* const* d_in, const int* in_sizes, int n_in,
                              void* d_out, int out_size, void* d_ws, size_t ws_size,
                              hipStream_t stream) {
  const float* x_in   = (const float*)d_in[0];
  const float* ln1_g  = (const float*)d_in[1];
  const float* ln1_b  = (const float*)d_in[2];
  const float* ln2_g  = (const float*)d_in[3];
  const float* ln2_b  = (const float*)d_in[4];
  const float* qkv_dw = (const float*)d_in[5];
  const float* qkv_bng = (const float*)d_in[6];
  const float* qkv_bnb = (const float*)d_in[7];
  const float* qkv_bnm = (const float*)d_in[8];
  const float* qkv_bnv = (const float*)d_in[9];
  const float* qkv_pw = (const float*)d_in[10];
  const float* position = (const float*)d_in[11];
  const float* c1d_w  = (const float*)d_in[12];
  const float* c1d_b  = (const float*)d_in[13];
  const float* lin_w  = (const float*)d_in[14];
  const float* lin_b  = (const float*)d_in[15];
  const float* f1_w   = (const float*)d_in[16];
  const float* f1_b   = (const float*)d_in[17];
  const float* fdw_w  = (const float*)d_in[18];
  const float* fdw_b  = (const float*)d_in[19];
  const float* f_bng  = (const float*)d_in[20];
  const float* f_bnb  = (const float*)d_in[21];
  const float* f_bnm  = (const float*)d_in[22];
  const float* f_bnv  = (const float*)d_in[23];
  const float* fpw_w  = (const float*)d_in[24];
  const float* fpw_b  = (const float*)d_in[25];
  const float* f2_w   = (const float*)d_in[26];
  const float* f2_b   = (const float*)d_in[27];

  float* xbuf = (float*)d_out;                 // running x lives in d_out
  short* qkvA = (short*)d_ws;                  // 7680
  short* linb = qkvA + 7680;                   // 262144
  short* f1wb = linb + 262144;                 // 10240
  short* img  = f1wb + 10240;                  // 48640
  float* convW = (float*)(img + 48640);        // 2304
  float* convB = convW + 2304;                 // 256
  float* qkvdw = convB + 256;                  // 1728
  float* qkvdb = qkvdw + 1728;                 // 192

  k_prep<<<1024, 256, 0, stream>>>(f1_w, fpw_w, f2_w, qkv_pw, lin_w,
      fdw_w, fdw_b, f_bng, f_bnb, f_bnm, f_bnv,
      qkv_dw, qkv_bng, qkv_bnb, qkv_bnm, qkv_bnv,
      qkvA, linb, f1wb, img, convW, convB, qkvdw, qkvdb);
  for (int l = 0; l < 2; l++) {
    const float* xin = (l == 0) ? x_in : xbuf;
    k_att3<<<B_, 512, 0, stream>>>(xin, ln1_g + l * 512, ln1_b + l * 512,
        qkvdw + l * 864, qkvdb + l * 96, qkvA + l * 3840,
        position + l * 1024, c1d_w + l * 128, c1d_b + l * 16,
        linb + l * 131072, lin_b + l * 512, xbuf);
    k_ffn4<<<B_, 1024, 0, stream>>>(xbuf, ln2_g + l * 512, ln2_b + l * 512,
        f1wb + l * 5120, f1_b + l * 128, convW + l * 1152, convB + l * 128,
        img + l * 24320, fpw_b + l * 128, f2_b + l * 32, xbuf);
  }
}

// Round 13
// 392.649 us; speedup vs baseline: 1.0446x; 1.0343x over previous
//
#include <hip/hip_runtime.h>
#include <hip/hip_bf16.h>

#define B_ 2048
#define EPSF 1e-5f

typedef __attribute__((ext_vector_type(8))) short short8v;
typedef __attribute__((ext_vector_type(4))) short short4v;
typedef __attribute__((ext_vector_type(4))) float f32x4;

// float -> bf16 bits via compiler-native conversion
__device__ __forceinline__ short f2bf_s(float f) {
  __hip_bfloat16 h = __float2bfloat16(f);
  return *reinterpret_cast<const short*>(&h);
}
__device__ __forceinline__ float bf2f(short s) {
  return __uint_as_float(((unsigned)(unsigned short)s) << 16);
}

// ---------------- weight prep -------------------------------------------------
__global__ __launch_bounds__(256) void k_prep(
    const float* __restrict__ f1_w, const float* __restrict__ fpw_w,
    const float* __restrict__ f2_w, const float* __restrict__ qkv_pw,
    const float* __restrict__ lin_w, const float* __restrict__ fdw_w,
    const float* __restrict__ fdw_b, const float* __restrict__ f_bng,
    const float* __restrict__ f_bnb, const float* __restrict__ f_bnm,
    const float* __restrict__ f_bnv, const float* __restrict__ qkv_dw,
    const float* __restrict__ qkv_bng, const float* __restrict__ qkv_bnb,
    const float* __restrict__ qkv_bnm, const float* __restrict__ qkv_bnv,
    short* __restrict__ qkvA, short* __restrict__ linb,
    short* __restrict__ f1wb, short* __restrict__ img,
    float* __restrict__ convW, float* __restrict__ convB,
    float* __restrict__ qkvdw, float* __restrict__ qkvdb) {
  int i = blockIdx.x * 256 + threadIdx.x;
  if (i < 7680) {
    int l = i / 3840, r = i % 3840;
    int io = r / 40, c = r % 40;
    qkvA[i] = (c < 32) ? f2bf_s(qkv_pw[l * 3072 + io * 32 + c]) : (short)0;
  }
  if (i < 262144) linb[i] = f2bf_s(lin_w[i]);
  if (i < 10240) {
    int l = i / 5120, r = i % 5120, o = r / 40, kk = r % 40;
    f1wb[i] = (kk < 32) ? f2bf_s(f1_w[l * 4096 + o * 32 + kk]) : (short)0;
  }
  if (i < 48640) {
    int l = i / 24320, r = i % 24320;
    short val;
    if (r < 19456) {
      int o = r / 152, kk = r % 152;
      val = (kk < 128) ? f2bf_s(fpw_w[l * 16384 + o * 128 + kk]) : (short)0;
    } else {
      int r2 = r - 19456;
      int d = r2 / 152, kk = r2 % 152;
      val = (kk < 128) ? f2bf_s(f2_w[l * 4096 + d * 128 + kk]) : (short)0;
    }
    img[i] = val;
  }
  if (i < 256) {
    int l = i >> 7, c = i & 127;
    float scale = f_bng[l * 128 + c] * rsqrtf(f_bnv[l * 128 + c] + EPSF);
#pragma unroll
    for (int k = 0; k < 9; k++)
      convW[l * 1152 + k * 128 + c] = fdw_w[(l * 128 + c) * 9 + k] * scale;
    convB[l * 128 + c] =
        (fdw_b[l * 128 + c] - f_bnm[l * 128 + c]) * scale + f_bnb[l * 128 + c];
  }
  if (i < 192) {  // qkv conv BN fold: [l][3][9][32] + [l][3][32]
    int l = i / 96, iw = (i % 96) / 32, c = i % 32;
    int bi = l * 96 + iw * 32 + c;
    float scale = qkv_bng[bi] * rsqrtf(qkv_bnv[bi] + EPSF);
#pragma unroll
    for (int k = 0; k < 9; k++)
      qkvdw[((l * 3 + iw) * 9 + k) * 32 + c] =
          qkv_dw[(l * 96 + iw * 32 + c) * 9 + k] * scale;
    qkvdb[bi] = qkv_bnb[bi] - qkv_bnm[bi] * scale;
  }
}

// ---------------- K_ATT3: 1 sample/block, 512 threads, LDS 46592 -> 3/CU -----
// NOTE: no min-waves hint — (512,6) forced VGPR=40 and spilled (R12:
// WRITE_SIZE 2x output). Natural ~64 VGPR keeps 8 waves/SIMD eligible;
// occupancy is LDS-limited at 3 blocks/CU.
__global__ __launch_bounds__(512) void k_att3(
    const float* __restrict__ xin, const float* __restrict__ g,
    const float* __restrict__ beta, const float* __restrict__ qkvdw,
    const float* __restrict__ qkvdb, const short* __restrict__ qkvA,
    const float* __restrict__ posn, const float* __restrict__ c1w,
    const float* __restrict__ c1b, const short* __restrict__ linb,
    const float* __restrict__ lin_b, float* __restrict__ xout) {
  __shared__ __align__(16) char smem[46592];
  int tid = threadIdx.x;
  int lane = tid & 63, w8 = tid >> 6;           // 8 waves
  int row = lane & 15, kg = lane >> 4;

  float* sc  = (float*)smem;
  short* pbf = (short*)smem;
  short* pa  = (short*)(smem + 4224);
  short* ore = (short*)(smem + 6784);
  short* t3s = (short*)(smem + 16896);
  short* xc1 = (short*)(smem + 16896);
  short* qe  = (short*)(smem + 32256);
  short* ke  = (short*)(smem + 36864);
  short* vt  = (short*)(smem + 41472);

  int b = blockIdx.x;
  const float* xb = xin + (size_t)b * 8192;
  float* xo = xout + (size_t)b * 8192;

  // ---- early prefetches ----
  float xr[4][4];
#pragma unroll
  for (int t = 0; t < 4; t++)
#pragma unroll
    for (int r = 0; r < 4; r++)
      xr[t][r] = xb[(kg * 4 + r) * 512 + (w8 * 4 + t) * 16 + row];
  int mi_pw = w8 & 1;
  short8v aq[3];
#pragma unroll
  for (int iw = 0; iw < 3; iw++)
    aq[iw] = *(const short8v*)&qkvA[(iw * 32 + mi_pw * 16 + row) * 40 + kg * 8];

  // ---- LN1 + to_patches -> pbf bf16 (2 rows per wave) ----
  for (int r = w8; r < 16; r += 8) {
    float vals[8];
    float sm = 0.f, ss = 0.f;
#pragma unroll
    for (int j = 0; j < 8; j++) {
      float t = xb[r * 512 + lane + j * 64];
      vals[j] = t; sm += t; ss += t * t;
    }
#pragma unroll
    for (int o = 32; o; o >>= 1) { sm += __shfl_xor(sm, o); ss += __shfl_xor(ss, o); }
    float m = sm * (1.f / 512.f);
    float inv = rsqrtf(ss * (1.f / 512.f) - m * m + EPSF);
#pragma unroll
    for (int j = 0; j < 8; j++) {
      int col = lane + j * 64;
      float nv = (vals[j] - m) * inv * g[col] + beta[col];
      pbf[(col >> 4) * 264 + r * 16 + (col & 15)] = f2bf_s(nv);
    }
  }
  __syncthreads();

  // ---- dw 3x3 s2 (+folded BN) x3 -> t3[iw][pos][c] ----
  {
    int c = tid & 31, oy = (tid >> 5) & 7, oxh = tid >> 8;
    int base = oxh * 8 - 1;
    float ra[9], rb[9], rc[9];
    int iy0 = 2 * oy - 1;
#pragma unroll
    for (int k = 0; k < 9; k++) {
      int ic = base + k;
      bool cv = (ic >= 0);
      ra[k] = (cv && iy0 >= 0) ? bf2f(pbf[c * 264 + iy0 * 16 + ic]) : 0.f;
      rb[k] = cv ? bf2f(pbf[c * 264 + (2 * oy) * 16 + ic]) : 0.f;
      rc[k] = cv ? bf2f(pbf[c * 264 + (2 * oy + 1) * 16 + ic]) : 0.f;
    }
    for (int iw = 0; iw < 3; iw++) {
      const float* w9 = qkvdw + iw * 288;
      float w00 = w9[0 * 32 + c], w01 = w9[1 * 32 + c], w02 = w9[2 * 32 + c];
      float w10 = w9[3 * 32 + c], w11 = w9[4 * 32 + c], w12 = w9[5 * 32 + c];
      float w20 = w9[6 * 32 + c], w21 = w9[7 * 32 + c], w22 = w9[8 * 32 + c];
      float shift = qkvdb[iw * 32 + c];
#pragma unroll
      for (int j = 0; j < 4; j++) {
        int ox = oxh * 4 + j;
        float acc = w00 * ra[2 * j] + w01 * ra[2 * j + 1] + w02 * ra[2 * j + 2]
                  + w10 * rb[2 * j] + w11 * rb[2 * j + 1] + w12 * rb[2 * j + 2]
                  + w20 * rc[2 * j] + w21 * rc[2 * j + 1] + w22 * rc[2 * j + 2];
        t3s[(iw * 64 + oy * 8 + ox) * 40 + c] = f2bf_s(acc + shift);
      }
    }
  }
  __syncthreads();

  // ---- pw MFMA (one 16x16 tile per wave per iw) -> qe, ke, vt ----
  {
    int mi = mi_pw, ni = w8 >> 1;                 // ni 0..3
    for (int iw = 0; iw < 3; iw++) {
      short8v bb = *(const short8v*)&t3s[(iw * 64 + ni * 16 + row) * 40 + kg * 8];
      f32x4 z = {};
      f32x4 acc = __builtin_amdgcn_mfma_f32_16x16x32_bf16(aq[iw], bb, z, 0, 0, 0);
      if (iw < 2) {
        short* tgt = (iw == 0) ? qe : ke;
#pragma unroll
        for (int r = 0; r < 4; r++) {
          int d = mi * 16 + kg * 4 + r;
          tgt[d * 72 + ni * 16 + row] = f2bf_s(acc[r]);
        }
      } else {
        int e = ni * 16 + row;
        int fb = mi * 16 + kg * 4;
        short4v v0;
        v0.x = f2bf_s(acc[0]); v0.y = f2bf_s(acc[1]);
        v0.z = f2bf_s(acc[2]); v0.w = f2bf_s(acc[3]);
        *(short4v*)&vt[e * 40 + fb] = v0;
      }
    }
  }
  __syncthreads();

  // ---- QK^T (waves 0-3) + position -> sc fp32 ----
  if (w8 < 4) {
    int mi = w8 & 1, ni = (w8 >> 1) & 1;
    f32x4 acc = {};
#pragma unroll
    for (int kk = 0; kk < 2; kk++) {
      short8v a = *(const short8v*)&qe[(mi * 16 + row) * 72 + kk * 32 + kg * 8];
      short8v bb = *(const short8v*)&ke[(ni * 16 + row) * 72 + kk * 32 + kg * 8];
      acc = __builtin_amdgcn_mfma_f32_16x16x32_bf16(a, bb, acc, 0, 0, 0);
    }
#pragma unroll
    for (int r = 0; r < 4; r++) {
      int d = mi * 16 + kg * 4 + r, f = ni * 16 + row;
      sc[d * 33 + f] = acc[r] * 0.125f + posn[d * 32 + f];
    }
  }
  __syncthreads();

  // ---- softmax (first 256 threads) ----
  if (tid < 256) {
    int srow = tid >> 3, sg = tid & 7;
    float v0 = sc[srow * 33 + sg * 4 + 0];
    float v1 = sc[srow * 33 + sg * 4 + 1];
    float v2 = sc[srow * 33 + sg * 4 + 2];
    float v3 = sc[srow * 33 + sg * 4 + 3];
    float mx = fmaxf(fmaxf(v0, v1), fmaxf(v2, v3));
    mx = fmaxf(mx, __shfl_xor(mx, 1));
    mx = fmaxf(mx, __shfl_xor(mx, 2));
    mx = fmaxf(mx, __shfl_xor(mx, 4));
    float e0 = __expf(v0 - mx), e1 = __expf(v1 - mx);
    float e2 = __expf(v2 - mx), e3 = __expf(v3 - mx);
    float sum = e0 + e1 + e2 + e3;
    sum += __shfl_xor(sum, 1); sum += __shfl_xor(sum, 2); sum += __shfl_xor(sum, 4);
    float inv = 1.f / sum;
    short4v pk;
    pk.x = f2bf_s(e0 * inv); pk.y = f2bf_s(e1 * inv);
    pk.z = f2bf_s(e2 * inv); pk.w = f2bf_s(e3 * inv);
    *(short4v*)&pa[srow * 40 + sg * 4] = pk;
  }
  __syncthreads();

  // ---- PV (one tile per wave) -> ore[p1][d*8+p2] ----
  {
    int mi = w8 & 1, et = w8 >> 1;
    short8v a = *(const short8v*)&pa[(mi * 16 + row) * 40 + kg * 8];
    int e = et * 16 + row;
    short8v bb = *(const short8v*)&vt[e * 40 + kg * 8];
    f32x4 z = {};
    f32x4 acc = __builtin_amdgcn_mfma_f32_16x16x32_bf16(a, bb, z, 0, 0, 0);
#pragma unroll
    for (int r = 0; r < 4; r++) {
      int d = mi * 16 + kg * 4 + r;
      ore[(e >> 3) * 264 + d * 8 + (e & 7)] = f2bf_s(acc[r]);
    }
  }
  __syncthreads();

  // ---- c1d: thread = (n, uh) ----
  {
    int n = tid & 255, uh = tid >> 8;
    float o8[8];
#pragma unroll
    for (int c = 0; c < 8; c++) o8[c] = bf2f(ore[c * 264 + n]);
#pragma unroll
    for (int uu = 0; uu < 8; uu++) {
      int u = uh * 8 + uu;
      float acc = c1b[u];
#pragma unroll
      for (int c = 0; c < 8; c++) acc += c1w[u * 8 + c] * o8[c];
      xc1[u * 264 + n] = f2bf_s(acc);
    }
  }
  __syncthreads();

  // ---- lin MFMA (4 tiles per wave) + bias + residual ----
  {
    short8v a8[8];
#pragma unroll
    for (int kk = 0; kk < 8; kk++)
      a8[kk] = *(const short8v*)&xc1[row * 264 + kk * 32 + kg * 8];
#pragma unroll
    for (int t = 0; t < 4; t++) {
      int nt = w8 * 4 + t;
      const short* bb_base = linb + (nt * 16 + row) * 256 + kg * 8;
      f32x4 acc = {};
#pragma unroll
      for (int kk = 0; kk < 8; kk++) {
        short8v bb = *(const short8v*)(bb_base + kk * 32);
        acc = __builtin_amdgcn_mfma_f32_16x16x32_bf16(a8[kk], bb, acc, 0, 0, 0);
      }
      int m = nt * 16 + row;
      float lb = lin_b[m];
#pragma unroll
      for (int r = 0; r < 4; r++) {
        int u = kg * 4 + r;
        xo[u * 512 + m] = xr[t][r] + acc[r] + lb;
      }
    }
  }
}

// ---------------- K_FFN4: 1024 threads, staged weights, vector conv ----------
__global__ __launch_bounds__(1024, 4) void k_ffn4(
    const float* __restrict__ x, const float* __restrict__ g,
    const float* __restrict__ beta, const short* __restrict__ f1wg,
    const float* __restrict__ f1b, const float* __restrict__ convW,
    const float* __restrict__ convB, const short* __restrict__ img,
    const float* __restrict__ pwbias, const float* __restrict__ f2b,
    float* __restrict__ xg) {
  __shared__ __align__(16) char smem[149504];
  short* p_lds = (short*)smem;                 // [256][40]
  short* f1w_lds = (short*)(smem + 20480);     // [128][40]
  short* sT = (short*)smem;                    // [256][152]
  short* sY = (short*)(smem + 77824);          // [128][280]
  short* pw_lds = (short*)(smem + 77824);      // [128][152]
  short* f2w_lds = (short*)(smem + 77824 + 38912);

  int b = blockIdx.x, tid = threadIdx.x;
  int lane = tid & 63, wid = tid >> 6;         // wid 0..15
  int row = lane & 15, kg = lane >> 4;
  const float* xb = x + (size_t)b * 8192;
  float* xo = xg + (size_t)b * 8192;

  // ---- prefetch pw/f2 weight image into regs ----
  const uint4* imgu = (const uint4*)img;
  uint4 pf0 = imgu[tid], pf1 = imgu[tid + 1024];
  uint4 pf2 = {};
  if (tid < 992) pf2 = imgu[tid + 2048];

  // ---- prefetch conv weights + all biases (hide L2 latency) ----
  int cch = tid & 127;
  float w_[9];
#pragma unroll
  for (int k = 0; k < 9; k++) w_[k] = convW[k * 128 + cch];
  float cb = convB[cch];
  int o0 = (wid & 3) * 32;
  float f1bv[8], pwbv[8], f2bv[8];
#pragma unroll
  for (int j = 0; j < 4; j++) {
    f1bv[j]     = f1b[o0 + kg * 4 + j];
    f1bv[4 + j] = f1b[o0 + 16 + kg * 4 + j];
    pwbv[j]     = pwbias[o0 + kg * 4 + j];
    pwbv[4 + j] = pwbias[o0 + 16 + kg * 4 + j];
    f2bv[j]     = f2b[kg * 4 + j];
    f2bv[4 + j] = f2b[16 + kg * 4 + j];
  }

  // ---- early residual loads (T14): matches f2 store pattern ----
  float xr[2][4];
#pragma unroll
  for (int mi = 0; mi < 2; mi++)
#pragma unroll
    for (int r2 = 0; r2 < 4; r2++)
      xr[mi][r2] = xo[wid * 512 + mi * 256 + kg * 64 + r2 * 16 + row];

  // ---- stage f1w ----
  if (tid < 640) ((uint4*)f1w_lds)[tid] = ((const uint4*)f1wg)[tid];

  // ---- LN2 + patches -> p_lds [pos][40] bf16 (one row per wave) ----
  {
    int r = wid;
    float vals[8];
    float s = 0.f, ss = 0.f;
#pragma unroll
    for (int j = 0; j < 8; j++) {
      float t = xb[r * 512 + lane + j * 64];
      vals[j] = t; s += t; ss += t * t;
    }
#pragma unroll
    for (int o = 32; o; o >>= 1) { s += __shfl_xor(s, o); ss += __shfl_xor(ss, o); }
    float m = s * (1.f / 512.f);
    float inv = rsqrtf(ss * (1.f / 512.f) - m * m + EPSF);
#pragma unroll
    for (int j = 0; j < 8; j++) {
      int col = lane + j * 64;
      float nv = (vals[j] - m) * inv * g[col] + beta[col];
      p_lds[(r * 16 + (col & 15)) * 40 + (col >> 4)] = f2bf_s(nv);
    }
  }
  __syncthreads();

  // ---- f1 MFMA: y1[o=128][pos=256], K=32; wave tile 32x64 ----
  {
    int pos0 = (wid >> 2) * 64;
    short8v a0 = *(const short8v*)&f1w_lds[(o0 + row) * 40 + kg * 8];
    short8v a1 = *(const short8v*)&f1w_lds[(o0 + 16 + row) * 40 + kg * 8];
#pragma unroll
    for (int ni = 0; ni < 4; ni++) {
      short8v bb = *(const short8v*)&p_lds[(pos0 + ni * 16 + row) * 40 + kg * 8];
      f32x4 z = {};
      f32x4 c0 = __builtin_amdgcn_mfma_f32_16x16x32_bf16(a0, bb, z, 0, 0, 0);
      f32x4 c1 = __builtin_amdgcn_mfma_f32_16x16x32_bf16(a1, bb, z, 0, 0, 0);
      int pos = pos0 + ni * 16 + row;
#pragma unroll
      for (int r2 = 0; r2 < 4; r2++) {
        int c = o0 + kg * 4 + r2;
        sY[c * 280 + pos] = f2bf_s(fmaxf(c0[r2] + f1bv[r2], 0.f));
        sY[(c + 16) * 280 + pos] = f2bf_s(fmaxf(c1[r2] + f1bv[4 + r2], 0.f));
      }
    }
  }
  __syncthreads();

  // ---- depthwise 3x3 s1 (+folded BN) -> sT [pos][152] bf16 ----
  {
    int c = cch, strip = tid >> 7;             // 2 rows per thread
#pragma unroll
    for (int j = 0; j < 2; j++) {
      int h = strip * 2 + j;
      float acc[16];
#pragma unroll
      for (int w = 0; w < 16; w++) acc[w] = cb;
#pragma unroll
      for (int rr = 0; rr < 3; rr++) {
        int rg = h - 1 + rr;
        if (rg < 0 || rg > 15) continue;
        short8v s0 = *(const short8v*)&sY[c * 280 + rg * 16];
        short8v s1 = *(const short8v*)&sY[c * 280 + rg * 16 + 8];
        float f[18];
        f[0] = 0.f; f[17] = 0.f;
#pragma unroll
        for (int i = 0; i < 8; i++) { f[1 + i] = bf2f(s0[i]); f[9 + i] = bf2f(s1[i]); }
        float w0 = w_[rr * 3], w1 = w_[rr * 3 + 1], w2 = w_[rr * 3 + 2];
#pragma unroll
        for (int w = 0; w < 16; w++)
          acc[w] += w0 * f[w] + w1 * f[w + 1] + w2 * f[w + 2];
      }
#pragma unroll
      for (int w = 0; w < 16; w++)
        sT[(h * 16 + w) * 152 + c] = f2bf_s(acc[w]);
    }
  }
  __syncthreads();

  // ---- drop prefetched weights into sY region ----
  {
    uint4* wdst = (uint4*)pw_lds;
    wdst[tid] = pf0; wdst[tid + 1024] = pf1;
    if (tid < 992) wdst[tid + 2048] = pf2;
  }
  __syncthreads();

  // ---- fpw MFMA: r[o=128][pos=256], K=128; wave tile 32x64 ----
  int pos0 = (wid >> 2) * 64;
  f32x4 facc[2][4] = {};
#pragma unroll
  for (int kk = 0; kk < 4; kk++) {
    int k0 = kk * 32 + kg * 8;
    short8v a0 = *(const short8v*)&pw_lds[(o0 + row) * 152 + k0];
    short8v a1 = *(const short8v*)&pw_lds[(o0 + 16 + row) * 152 + k0];
    short8v bb[4];
#pragma unroll
    for (int ni = 0; ni < 4; ni++)
      bb[ni] = *(const short8v*)&sT[(pos0 + ni * 16 + row) * 152 + k0];
#pragma unroll
    for (int ni = 0; ni < 4; ni++) {
      facc[0][ni] = __builtin_amdgcn_mfma_f32_16x16x32_bf16(a0, bb[ni], facc[0][ni], 0, 0, 0);
      facc[1][ni] = __builtin_amdgcn_mfma_f32_16x16x32_bf16(a1, bb[ni], facc[1][ni], 0, 0, 0);
    }
  }
  __syncthreads();

  // ---- bias + ReLU -> sT[pos][o] (overwrite) ----
#pragma unroll
  for (int mi = 0; mi < 2; mi++) {
    int ob = o0 + mi * 16 + kg * 4;
#pragma unroll
    for (int ni = 0; ni < 4; ni++) {
      int pos = pos0 + ni * 16 + row;
      short4v pk;
      pk.x = f2bf_s(fmaxf(facc[mi][ni][0] + pwbv[mi * 4 + 0], 0.f));
      pk.y = f2bf_s(fmaxf(facc[mi][ni][1] + pwbv[mi * 4 + 1], 0.f));
      pk.z = f2bf_s(fmaxf(facc[mi][ni][2] + pwbv[mi * 4 + 2], 0.f));
      pk.w = f2bf_s(fmaxf(facc[mi][ni][3] + pwbv[mi * 4 + 3], 0.f));
      *(short4v*)&sT[pos * 152 + ob] = pk;
    }
  }
  __syncthreads();

  // ---- f2 MFMA: out[d=32][pos=256], K=128; direct residual store ----
  {
    f32x4 acc2[2] = {};
    int pos = wid * 16 + row;
#pragma unroll
    for (int kk = 0; kk < 4; kk++) {
      int k0 = kk * 32 + kg * 8;
      short8v a0 = *(const short8v*)&f2w_lds[row * 152 + k0];
      short8v a1 = *(const short8v*)&f2w_lds[(16 + row) * 152 + k0];
      short8v bb = *(const short8v*)&sT[pos * 152 + k0];
      acc2[0] = __builtin_amdgcn_mfma_f32_16x16x32_bf16(a0, bb, acc2[0], 0, 0, 0);
      acc2[1] = __builtin_amdgcn_mfma_f32_16x16x32_bf16(a1, bb, acc2[1], 0, 0, 0);
    }
#pragma unroll
    for (int mi = 0; mi < 2; mi++)
#pragma unroll
      for (int r2 = 0; r2 < 4; r2++) {
        xo[wid * 512 + mi * 256 + kg * 64 + r2 * 16 + row] =
            xr[mi][r2] + acc2[mi][r2] + f2bv[mi * 4 + r2];
      }
  }
}

extern "C" void kernel_launch(void* const* d_in, const int* in_sizes, int n_in,
                              void* d_out, int out_size, void* d_ws, size_t ws_size,
                              hipStream_t stream) {
  const float* x_in   = (const float*)d_in[0];
  const float* ln1_g  = (const float*)d_in[1];
  const float* ln1_b  = (const float*)d_in[2];
  const float* ln2_g  = (const float*)d_in[3];
  const float* ln2_b  = (const float*)d_in[4];
  const float* qkv_dw = (const float*)d_in[5];
  const float* qkv_bng = (const float*)d_in[6];
  const float* qkv_bnb = (const float*)d_in[7];
  const float* qkv_bnm = (const float*)d_in[8];
  const float* qkv_bnv = (const float*)d_in[9];
  const float* qkv_pw = (const float*)d_in[10];
  const float* position = (const float*)d_in[11];
  const float* c1d_w  = (const float*)d_in[12];
  const float* c1d_b  = (const float*)d_in[13];
  const float* lin_w  = (const float*)d_in[14];
  const float* lin_b  = (const float*)d_in[15];
  const float* f1_w   = (const float*)d_in[16];
  const float* f1_b   = (const float*)d_in[17];
  const float* fdw_w  = (const float*)d_in[18];
  const float* fdw_b  = (const float*)d_in[19];
  const float* f_bng  = (const float*)d_in[20];
  const float* f_bnb  = (const float*)d_in[21];
  const float* f_bnm  = (const float*)d_in[22];
  const float* f_bnv  = (const float*)d_in[23];
  const float* fpw_w  = (const float*)d_in[24];
  const float* fpw_b  = (const float*)d_in[25];
  const float* f2_w   = (const float*)d_in[26];
  const float* f2_b   = (const float*)d_in[27];

  float* xbuf = (float*)d_out;                 // running x lives in d_out
  short* qkvA = (short*)d_ws;                  // 7680
  short* linb = qkvA + 7680;                   // 262144
  short* f1wb = linb + 262144;                 // 10240
  short* img  = f1wb + 10240;                  // 48640
  float* convW = (float*)(img + 48640);        // 2304
  float* convB = convW + 2304;                 // 256
  float* qkvdw = convB + 256;                  // 1728
  float* qkvdb = qkvdw + 1728;                 // 192

  k_prep<<<1024, 256, 0, stream>>>(f1_w, fpw_w, f2_w, qkv_pw, lin_w,
      fdw_w, fdw_b, f_bng, f_bnb, f_bnm, f_bnv,
      qkv_dw, qkv_bng, qkv_bnb, qkv_bnm, qkv_bnv,
      qkvA, linb, f1wb, img, convW, convB, qkvdw, qkvdb);
  for (int l = 0; l < 2; l++) {
    const float* xin = (l == 0) ? x_in : xbuf;
    k_att3<<<B_, 512, 0, stream>>>(xin, ln1_g + l * 512, ln1_b + l * 512,
        qkvdw + l * 864, qkvdb + l * 96, qkvA + l * 3840,
        position + l * 1024, c1d_w + l * 128, c1d_b + l * 16,
        linb + l * 131072, lin_b + l * 512, xbuf);
    k_ffn4<<<B_, 1024, 0, stream>>>(xbuf, ln2_g + l * 512, ln2_b + l * 512,
        f1wb + l * 5120, f1_b + l * 128, convW + l * 1152, convB + l * 128,
        img + l * 24320, fpw_b + l * 128, f2_b + l * 32, xbuf);
  }
}

// Round 14
// 384.340 us; speedup vs baseline: 1.0672x; 1.0216x over previous
//
#include <hip/hip_runtime.h>
#include <hip/hip_bf16.h>

#define B_ 2048
#define EPSF 1e-5f

typedef __attribute__((ext_vector_type(8))) short short8v;
typedef __attribute__((ext_vector_type(4))) short short4v;
typedef __attribute__((ext_vector_type(4))) float f32x4;

// float -> bf16 bits via compiler-native conversion
__device__ __forceinline__ short f2bf_s(float f) {
  __hip_bfloat16 h = __float2bfloat16(f);
  return *reinterpret_cast<const short*>(&h);
}
__device__ __forceinline__ float bf2f(short s) {
  return __uint_as_float(((unsigned)(unsigned short)s) << 16);
}

// ---------------- weight prep -------------------------------------------------
__global__ __launch_bounds__(256) void k_prep(
    const float* __restrict__ f1_w, const float* __restrict__ fpw_w,
    const float* __restrict__ f2_w, const float* __restrict__ qkv_pw,
    const float* __restrict__ lin_w, const float* __restrict__ fdw_w,
    const float* __restrict__ fdw_b, const float* __restrict__ f_bng,
    const float* __restrict__ f_bnb, const float* __restrict__ f_bnm,
    const float* __restrict__ f_bnv, const float* __restrict__ qkv_dw,
    const float* __restrict__ qkv_bng, const float* __restrict__ qkv_bnb,
    const float* __restrict__ qkv_bnm, const float* __restrict__ qkv_bnv,
    short* __restrict__ qkvA, short* __restrict__ linb,
    short* __restrict__ f1wb, short* __restrict__ img,
    float* __restrict__ convW, float* __restrict__ convB,
    float* __restrict__ qkvdw, float* __restrict__ qkvdb) {
  int i = blockIdx.x * 256 + threadIdx.x;
  if (i < 7680) {
    int l = i / 3840, r = i % 3840;
    int io = r / 40, c = r % 40;
    qkvA[i] = (c < 32) ? f2bf_s(qkv_pw[l * 3072 + io * 32 + c]) : (short)0;
  }
  if (i < 262144) linb[i] = f2bf_s(lin_w[i]);
  if (i < 10240) {
    int l = i / 5120, r = i % 5120, o = r / 40, kk = r % 40;
    f1wb[i] = (kk < 32) ? f2bf_s(f1_w[l * 4096 + o * 32 + kk]) : (short)0;
  }
  if (i < 48640) {
    int l = i / 24320, r = i % 24320;
    short val;
    if (r < 19456) {
      int o = r / 152, kk = r % 152;
      val = (kk < 128) ? f2bf_s(fpw_w[l * 16384 + o * 128 + kk]) : (short)0;
    } else {
      int r2 = r - 19456;
      int d = r2 / 152, kk = r2 % 152;
      val = (kk < 128) ? f2bf_s(f2_w[l * 4096 + d * 128 + kk]) : (short)0;
    }
    img[i] = val;
  }
  if (i < 256) {
    int l = i >> 7, c = i & 127;
    float scale = f_bng[l * 128 + c] * rsqrtf(f_bnv[l * 128 + c] + EPSF);
#pragma unroll
    for (int k = 0; k < 9; k++)
      convW[l * 1152 + k * 128 + c] = fdw_w[(l * 128 + c) * 9 + k] * scale;
    convB[l * 128 + c] =
        (fdw_b[l * 128 + c] - f_bnm[l * 128 + c]) * scale + f_bnb[l * 128 + c];
  }
  if (i < 192) {  // qkv conv BN fold: [l][3][9][32] + [l][3][32]
    int l = i / 96, iw = (i % 96) / 32, c = i % 32;
    int bi = l * 96 + iw * 32 + c;
    float scale = qkv_bng[bi] * rsqrtf(qkv_bnv[bi] + EPSF);
#pragma unroll
    for (int k = 0; k < 9; k++)
      qkvdw[((l * 3 + iw) * 9 + k) * 32 + c] =
          qkv_dw[(l * 96 + iw * 32 + c) * 9 + k] * scale;
    qkvdb[bi] = qkv_bnb[bi] - qkv_bnm[bi] * scale;
  }
}

// ---------------- K_ATT3: 1 sample/block, 512 threads, LDS 48768 -> 3/CU -----
// Conflict-tuned strides: pbf 266 (bank-stride 5, scalar reads conflict-free),
// qe/ke 88 and xc1 280 (bank-stride 12: rows 0-7 cover all 32 banks once).
// LDS overlay:
//   pbf [32][266] bf16 @0      (17024)  -- overlays after conv:
//       sc fp32 [32][33] @0    (4224)
//       pa  [32][40]  @4224    (2560)
//       ore [8][264]  @6784    (4224)
//   t3s [3][64][40] @17024     (15360)  -- overlay: xc1 [16][280] @17024
//   qe  [32][88]  @32384       (5632)
//   ke  [32][88]  @38016       (5632)
//   vt  [64][40]  @43648       (5120)   -> total 48768
__global__ __launch_bounds__(512) void k_att3(
    const float* __restrict__ xin, const float* __restrict__ g,
    const float* __restrict__ beta, const float* __restrict__ qkvdw,
    const float* __restrict__ qkvdb, const short* __restrict__ qkvA,
    const float* __restrict__ posn, const float* __restrict__ c1w,
    const float* __restrict__ c1b, const short* __restrict__ linb,
    const float* __restrict__ lin_b, float* __restrict__ xout) {
  __shared__ __align__(16) char smem[48768];
  int tid = threadIdx.x;
  int lane = tid & 63, w8 = tid >> 6;           // 8 waves
  int row = lane & 15, kg = lane >> 4;

  float* sc  = (float*)smem;
  short* pbf = (short*)smem;
  short* pa  = (short*)(smem + 4224);
  short* ore = (short*)(smem + 6784);
  short* t3s = (short*)(smem + 17024);
  short* xc1 = (short*)(smem + 17024);
  short* qe  = (short*)(smem + 32384);
  short* ke  = (short*)(smem + 38016);
  short* vt  = (short*)(smem + 43648);

  int b = blockIdx.x;
  const float* xb = xin + (size_t)b * 8192;
  float* xo = xout + (size_t)b * 8192;

  // ---- early prefetches ----
  float xr[4][4];
#pragma unroll
  for (int t = 0; t < 4; t++)
#pragma unroll
    for (int r = 0; r < 4; r++)
      xr[t][r] = xb[(kg * 4 + r) * 512 + (w8 * 4 + t) * 16 + row];
  int mi_pw = w8 & 1;
  short8v aq[3];
#pragma unroll
  for (int iw = 0; iw < 3; iw++)
    aq[iw] = *(const short8v*)&qkvA[(iw * 32 + mi_pw * 16 + row) * 40 + kg * 8];

  // ---- LN1 + to_patches -> pbf bf16 (2 rows per wave) ----
  for (int r = w8; r < 16; r += 8) {
    float vals[8];
    float sm = 0.f, ss = 0.f;
#pragma unroll
    for (int j = 0; j < 8; j++) {
      float t = xb[r * 512 + lane + j * 64];
      vals[j] = t; sm += t; ss += t * t;
    }
#pragma unroll
    for (int o = 32; o; o >>= 1) { sm += __shfl_xor(sm, o); ss += __shfl_xor(ss, o); }
    float m = sm * (1.f / 512.f);
    float inv = rsqrtf(ss * (1.f / 512.f) - m * m + EPSF);
#pragma unroll
    for (int j = 0; j < 8; j++) {
      int col = lane + j * 64;
      float nv = (vals[j] - m) * inv * g[col] + beta[col];
      pbf[(col >> 4) * 266 + r * 16 + (col & 15)] = f2bf_s(nv);
    }
  }
  __syncthreads();

  // ---- dw 3x3 s2 (+folded BN) x3 -> t3[iw][pos][c] ----
  {
    int c = tid & 31, oy = (tid >> 5) & 7, oxh = tid >> 8;
    int base = oxh * 8 - 1;
    float ra[9], rb[9], rc[9];
    int iy0 = 2 * oy - 1;
#pragma unroll
    for (int k = 0; k < 9; k++) {
      int ic = base + k;
      bool cv = (ic >= 0);
      ra[k] = (cv && iy0 >= 0) ? bf2f(pbf[c * 266 + iy0 * 16 + ic]) : 0.f;
      rb[k] = cv ? bf2f(pbf[c * 266 + (2 * oy) * 16 + ic]) : 0.f;
      rc[k] = cv ? bf2f(pbf[c * 266 + (2 * oy + 1) * 16 + ic]) : 0.f;
    }
    for (int iw = 0; iw < 3; iw++) {
      const float* w9 = qkvdw + iw * 288;
      float w00 = w9[0 * 32 + c], w01 = w9[1 * 32 + c], w02 = w9[2 * 32 + c];
      float w10 = w9[3 * 32 + c], w11 = w9[4 * 32 + c], w12 = w9[5 * 32 + c];
      float w20 = w9[6 * 32 + c], w21 = w9[7 * 32 + c], w22 = w9[8 * 32 + c];
      float shift = qkvdb[iw * 32 + c];
#pragma unroll
      for (int j = 0; j < 4; j++) {
        int ox = oxh * 4 + j;
        float acc = w00 * ra[2 * j] + w01 * ra[2 * j + 1] + w02 * ra[2 * j + 2]
                  + w10 * rb[2 * j] + w11 * rb[2 * j + 1] + w12 * rb[2 * j + 2]
                  + w20 * rc[2 * j] + w21 * rc[2 * j + 1] + w22 * rc[2 * j + 2];
        t3s[(iw * 64 + oy * 8 + ox) * 40 + c] = f2bf_s(acc + shift);
      }
    }
  }
  __syncthreads();

  // ---- pw MFMA (one 16x16 tile per wave per iw) -> qe, ke, vt ----
  {
    int mi = mi_pw, ni = w8 >> 1;                 // ni 0..3
    for (int iw = 0; iw < 3; iw++) {
      short8v bb = *(const short8v*)&t3s[(iw * 64 + ni * 16 + row) * 40 + kg * 8];
      f32x4 z = {};
      f32x4 acc = __builtin_amdgcn_mfma_f32_16x16x32_bf16(aq[iw], bb, z, 0, 0, 0);
      if (iw < 2) {
        short* tgt = (iw == 0) ? qe : ke;
#pragma unroll
        for (int r = 0; r < 4; r++) {
          int d = mi * 16 + kg * 4 + r;
          tgt[d * 88 + ni * 16 + row] = f2bf_s(acc[r]);
        }
      } else {
        int e = ni * 16 + row;
        int fb = mi * 16 + kg * 4;
        short4v v0;
        v0.x = f2bf_s(acc[0]); v0.y = f2bf_s(acc[1]);
        v0.z = f2bf_s(acc[2]); v0.w = f2bf_s(acc[3]);
        *(short4v*)&vt[e * 40 + fb] = v0;
      }
    }
  }
  __syncthreads();

  // ---- QK^T (waves 0-3) + position -> sc fp32 ----
  if (w8 < 4) {
    int mi = w8 & 1, ni = (w8 >> 1) & 1;
    f32x4 acc = {};
#pragma unroll
    for (int kk = 0; kk < 2; kk++) {
      short8v a = *(const short8v*)&qe[(mi * 16 + row) * 88 + kk * 32 + kg * 8];
      short8v bb = *(const short8v*)&ke[(ni * 16 + row) * 88 + kk * 32 + kg * 8];
      acc = __builtin_amdgcn_mfma_f32_16x16x32_bf16(a, bb, acc, 0, 0, 0);
    }
#pragma unroll
    for (int r = 0; r < 4; r++) {
      int d = mi * 16 + kg * 4 + r, f = ni * 16 + row;
      sc[d * 33 + f] = acc[r] * 0.125f + posn[d * 32 + f];
    }
  }
  __syncthreads();

  // ---- softmax (first 256 threads) ----
  if (tid < 256) {
    int srow = tid >> 3, sg = tid & 7;
    float v0 = sc[srow * 33 + sg * 4 + 0];
    float v1 = sc[srow * 33 + sg * 4 + 1];
    float v2 = sc[srow * 33 + sg * 4 + 2];
    float v3 = sc[srow * 33 + sg * 4 + 3];
    float mx = fmaxf(fmaxf(v0, v1), fmaxf(v2, v3));
    mx = fmaxf(mx, __shfl_xor(mx, 1));
    mx = fmaxf(mx, __shfl_xor(mx, 2));
    mx = fmaxf(mx, __shfl_xor(mx, 4));
    float e0 = __expf(v0 - mx), e1 = __expf(v1 - mx);
    float e2 = __expf(v2 - mx), e3 = __expf(v3 - mx);
    float sum = e0 + e1 + e2 + e3;
    sum += __shfl_xor(sum, 1); sum += __shfl_xor(sum, 2); sum += __shfl_xor(sum, 4);
    float inv = 1.f / sum;
    short4v pk;
    pk.x = f2bf_s(e0 * inv); pk.y = f2bf_s(e1 * inv);
    pk.z = f2bf_s(e2 * inv); pk.w = f2bf_s(e3 * inv);
    *(short4v*)&pa[srow * 40 + sg * 4] = pk;
  }
  __syncthreads();

  // ---- PV (one tile per wave) -> ore[p1][d*8+p2] ----
  {
    int mi = w8 & 1, et = w8 >> 1;
    short8v a = *(const short8v*)&pa[(mi * 16 + row) * 40 + kg * 8];
    int e = et * 16 + row;
    short8v bb = *(const short8v*)&vt[e * 40 + kg * 8];
    f32x4 z = {};
    f32x4 acc = __builtin_amdgcn_mfma_f32_16x16x32_bf16(a, bb, z, 0, 0, 0);
#pragma unroll
    for (int r = 0; r < 4; r++) {
      int d = mi * 16 + kg * 4 + r;
      ore[(e >> 3) * 264 + d * 8 + (e & 7)] = f2bf_s(acc[r]);
    }
  }
  __syncthreads();

  // ---- c1d: thread = (n, uh) ----
  {
    int n = tid & 255, uh = tid >> 8;
    float o8[8];
#pragma unroll
    for (int c = 0; c < 8; c++) o8[c] = bf2f(ore[c * 264 + n]);
#pragma unroll
    for (int uu = 0; uu < 8; uu++) {
      int u = uh * 8 + uu;
      float acc = c1b[u];
#pragma unroll
      for (int c = 0; c < 8; c++) acc += c1w[u * 8 + c] * o8[c];
      xc1[u * 280 + n] = f2bf_s(acc);
    }
  }
  __syncthreads();

  // ---- lin MFMA (4 tiles per wave) + bias + residual ----
  {
    short8v a8[8];
#pragma unroll
    for (int kk = 0; kk < 8; kk++)
      a8[kk] = *(const short8v*)&xc1[row * 280 + kk * 32 + kg * 8];
#pragma unroll
    for (int t = 0; t < 4; t++) {
      int nt = w8 * 4 + t;
      const short* bb_base = linb + (nt * 16 + row) * 256 + kg * 8;
      f32x4 acc = {};
#pragma unroll
      for (int kk = 0; kk < 8; kk++) {
        short8v bb = *(const short8v*)(bb_base + kk * 32);
        acc = __builtin_amdgcn_mfma_f32_16x16x32_bf16(a8[kk], bb, acc, 0, 0, 0);
      }
      int m = nt * 16 + row;
      float lb = lin_b[m];
#pragma unroll
      for (int r = 0; r < 4; r++) {
        int u = kg * 4 + r;
        xo[u * 512 + m] = xr[t][r] + acc[r] + lb;
      }
    }
  }
}

// ---------------- K_FFN4: 1024 threads, staged weights, vector conv ----------
// (R10 form: inline bias reads — R11's bias prefetch cost ~3%)
__global__ __launch_bounds__(1024, 4) void k_ffn4(
    const float* __restrict__ x, const float* __restrict__ g,
    const float* __restrict__ beta, const short* __restrict__ f1wg,
    const float* __restrict__ f1b, const float* __restrict__ convW,
    const float* __restrict__ convB, const short* __restrict__ img,
    const float* __restrict__ pwbias, const float* __restrict__ f2b,
    float* __restrict__ xg) {
  __shared__ __align__(16) char smem[149504];
  short* p_lds = (short*)smem;                 // [256][40]
  short* f1w_lds = (short*)(smem + 20480);     // [128][40]
  short* sT = (short*)smem;                    // [256][152]
  short* sY = (short*)(smem + 77824);          // [128][280]
  short* pw_lds = (short*)(smem + 77824);      // [128][152]
  short* f2w_lds = (short*)(smem + 77824 + 38912);

  int b = blockIdx.x, tid = threadIdx.x;
  int lane = tid & 63, wid = tid >> 6;         // wid 0..15
  int row = lane & 15, kg = lane >> 4;
  const float* xb = x + (size_t)b * 8192;
  float* xo = xg + (size_t)b * 8192;

  // ---- prefetch pw/f2 weight image into regs ----
  const uint4* imgu = (const uint4*)img;
  uint4 pf0 = imgu[tid], pf1 = imgu[tid + 1024];
  uint4 pf2 = {};
  if (tid < 992) pf2 = imgu[tid + 2048];

  // ---- prefetch conv weights (hide L2 latency under LN/f1 phases) ----
  int cch = tid & 127;
  float w_[9];
#pragma unroll
  for (int k = 0; k < 9; k++) w_[k] = convW[k * 128 + cch];
  float cb = convB[cch];

  // ---- early residual loads (T14): matches f2 store pattern ----
  float xr[2][4];
#pragma unroll
  for (int mi = 0; mi < 2; mi++)
#pragma unroll
    for (int r2 = 0; r2 < 4; r2++)
      xr[mi][r2] = xo[wid * 512 + mi * 256 + kg * 64 + r2 * 16 + row];

  // ---- stage f1w ----
  if (tid < 640) ((uint4*)f1w_lds)[tid] = ((const uint4*)f1wg)[tid];

  // ---- LN2 + patches -> p_lds [pos][40] bf16 (one row per wave) ----
  {
    int r = wid;
    float vals[8];
    float s = 0.f, ss = 0.f;
#pragma unroll
    for (int j = 0; j < 8; j++) {
      float t = xb[r * 512 + lane + j * 64];
      vals[j] = t; s += t; ss += t * t;
    }
#pragma unroll
    for (int o = 32; o; o >>= 1) { s += __shfl_xor(s, o); ss += __shfl_xor(ss, o); }
    float m = s * (1.f / 512.f);
    float inv = rsqrtf(ss * (1.f / 512.f) - m * m + EPSF);
#pragma unroll
    for (int j = 0; j < 8; j++) {
      int col = lane + j * 64;
      float nv = (vals[j] - m) * inv * g[col] + beta[col];
      p_lds[(r * 16 + (col & 15)) * 40 + (col >> 4)] = f2bf_s(nv);
    }
  }
  __syncthreads();

  // ---- f1 MFMA: y1[o=128][pos=256], K=32; wave tile 32x64 ----
  {
    int o0 = (wid & 3) * 32, pos0 = (wid >> 2) * 64;
    short8v a0 = *(const short8v*)&f1w_lds[(o0 + row) * 40 + kg * 8];
    short8v a1 = *(const short8v*)&f1w_lds[(o0 + 16 + row) * 40 + kg * 8];
#pragma unroll
    for (int ni = 0; ni < 4; ni++) {
      short8v bb = *(const short8v*)&p_lds[(pos0 + ni * 16 + row) * 40 + kg * 8];
      f32x4 z = {};
      f32x4 c0 = __builtin_amdgcn_mfma_f32_16x16x32_bf16(a0, bb, z, 0, 0, 0);
      f32x4 c1 = __builtin_amdgcn_mfma_f32_16x16x32_bf16(a1, bb, z, 0, 0, 0);
      int pos = pos0 + ni * 16 + row;
#pragma unroll
      for (int r2 = 0; r2 < 4; r2++) {
        int c = o0 + kg * 4 + r2;
        sY[c * 280 + pos] = f2bf_s(fmaxf(c0[r2] + f1b[c], 0.f));
        sY[(c + 16) * 280 + pos] = f2bf_s(fmaxf(c1[r2] + f1b[c + 16], 0.f));
      }
    }
  }
  __syncthreads();

  // ---- depthwise 3x3 s1 (+folded BN) -> sT [pos][152] bf16 ----
  {
    int c = cch, strip = tid >> 7;             // 2 rows per thread
#pragma unroll
    for (int j = 0; j < 2; j++) {
      int h = strip * 2 + j;
      float acc[16];
#pragma unroll
      for (int w = 0; w < 16; w++) acc[w] = cb;
#pragma unroll
      for (int rr = 0; rr < 3; rr++) {
        int rg = h - 1 + rr;
        if (rg < 0 || rg > 15) continue;
        short8v s0 = *(const short8v*)&sY[c * 280 + rg * 16];
        short8v s1 = *(const short8v*)&sY[c * 280 + rg * 16 + 8];
        float f[18];
        f[0] = 0.f; f[17] = 0.f;
#pragma unroll
        for (int i = 0; i < 8; i++) { f[1 + i] = bf2f(s0[i]); f[9 + i] = bf2f(s1[i]); }
        float w0 = w_[rr * 3], w1 = w_[rr * 3 + 1], w2 = w_[rr * 3 + 2];
#pragma unroll
        for (int w = 0; w < 16; w++)
          acc[w] += w0 * f[w] + w1 * f[w + 1] + w2 * f[w + 2];
      }
#pragma unroll
      for (int w = 0; w < 16; w++)
        sT[(h * 16 + w) * 152 + c] = f2bf_s(acc[w]);
    }
  }
  __syncthreads();

  // ---- drop prefetched weights into sY region ----
  {
    uint4* wdst = (uint4*)pw_lds;
    wdst[tid] = pf0; wdst[tid + 1024] = pf1;
    if (tid < 992) wdst[tid + 2048] = pf2;
  }
  __syncthreads();

  // ---- fpw MFMA: r[o=128][pos=256], K=128; wave tile 32x64 ----
  int o0 = (wid & 3) * 32, pos0 = (wid >> 2) * 64;
  f32x4 facc[2][4] = {};
#pragma unroll
  for (int kk = 0; kk < 4; kk++) {
    int k0 = kk * 32 + kg * 8;
    short8v a0 = *(const short8v*)&pw_lds[(o0 + row) * 152 + k0];
    short8v a1 = *(const short8v*)&pw_lds[(o0 + 16 + row) * 152 + k0];
    short8v bb[4];
#pragma unroll
    for (int ni = 0; ni < 4; ni++)
      bb[ni] = *(const short8v*)&sT[(pos0 + ni * 16 + row) * 152 + k0];
#pragma unroll
    for (int ni = 0; ni < 4; ni++) {
      facc[0][ni] = __builtin_amdgcn_mfma_f32_16x16x32_bf16(a0, bb[ni], facc[0][ni], 0, 0, 0);
      facc[1][ni] = __builtin_amdgcn_mfma_f32_16x16x32_bf16(a1, bb[ni], facc[1][ni], 0, 0, 0);
    }
  }
  __syncthreads();

  // ---- bias + ReLU -> sT[pos][o] (overwrite) ----
#pragma unroll
  for (int mi = 0; mi < 2; mi++) {
    int ob = o0 + mi * 16 + kg * 4;
    float pb0 = pwbias[ob], pb1 = pwbias[ob + 1];
    float pb2 = pwbias[ob + 2], pb3 = pwbias[ob + 3];
#pragma unroll
    for (int ni = 0; ni < 4; ni++) {
      int pos = pos0 + ni * 16 + row;
      short4v pk;
      pk.x = f2bf_s(fmaxf(facc[mi][ni][0] + pb0, 0.f));
      pk.y = f2bf_s(fmaxf(facc[mi][ni][1] + pb1, 0.f));
      pk.z = f2bf_s(fmaxf(facc[mi][ni][2] + pb2, 0.f));
      pk.w = f2bf_s(fmaxf(facc[mi][ni][3] + pb3, 0.f));
      *(short4v*)&sT[pos * 152 + ob] = pk;
    }
  }
  __syncthreads();

  // ---- f2 MFMA: out[d=32][pos=256], K=128; direct residual store ----
  {
    f32x4 acc2[2] = {};
    int pos = wid * 16 + row;
#pragma unroll
    for (int kk = 0; kk < 4; kk++) {
      int k0 = kk * 32 + kg * 8;
      short8v a0 = *(const short8v*)&f2w_lds[row * 152 + k0];
      short8v a1 = *(const short8v*)&f2w_lds[(16 + row) * 152 + k0];
      short8v bb = *(const short8v*)&sT[pos * 152 + k0];
      acc2[0] = __builtin_amdgcn_mfma_f32_16x16x32_bf16(a0, bb, acc2[0], 0, 0, 0);
      acc2[1] = __builtin_amdgcn_mfma_f32_16x16x32_bf16(a1, bb, acc2[1], 0, 0, 0);
    }
#pragma unroll
    for (int mi = 0; mi < 2; mi++)
#pragma unroll
      for (int r2 = 0; r2 < 4; r2++) {
        int d = mi * 16 + kg * 4 + r2;
        xo[wid * 512 + mi * 256 + kg * 64 + r2 * 16 + row] =
            xr[mi][r2] + acc2[mi][r2] + f2b[d];
      }
  }
}

extern "C" void kernel_launch(void* const* d_in, const int* in_sizes, int n_in,
                              void* d_out, int out_size, void* d_ws, size_t ws_size,
                              hipStream_t stream) {
  const float* x_in   = (const float*)d_in[0];
  const float* ln1_g  = (const float*)d_in[1];
  const float* ln1_b  = (const float*)d_in[2];
  const float* ln2_g  = (const float*)d_in[3];
  const float* ln2_b  = (const float*)d_in[4];
  const float* qkv_dw = (const float*)d_in[5];
  const float* qkv_bng = (const float*)d_in[6];
  const float* qkv_bnb = (const float*)d_in[7];
  const float* qkv_bnm = (const float*)d_in[8];
  const float* qkv_bnv = (const float*)d_in[9];
  const float* qkv_pw = (const float*)d_in[10];
  const float* position = (const float*)d_in[11];
  const float* c1d_w  = (const float*)d_in[12];
  const float* c1d_b  = (const float*)d_in[13];
  const float* lin_w  = (const float*)d_in[14];
  const float* lin_b  = (const float*)d_in[15];
  const float* f1_w   = (const float*)d_in[16];
  const float* f1_b   = (const float*)d_in[17];
  const float* fdw_w  = (const float*)d_in[18];
  const float* fdw_b  = (const float*)d_in[19];
  const float* f_bng  = (const float*)d_in[20];
  const float* f_bnb  = (const float*)d_in[21];
  const float* f_bnm  = (const float*)d_in[22];
  const float* f_bnv  = (const float*)d_in[23];
  const float* fpw_w  = (const float*)d_in[24];
  const float* fpw_b  = (const float*)d_in[25];
  const float* f2_w   = (const float*)d_in[26];
  const float* f2_b   = (const float*)d_in[27];

  float* xbuf = (float*)d_out;                 // running x lives in d_out
  short* qkvA = (short*)d_ws;                  // 7680
  short* linb = qkvA + 7680;                   // 262144
  short* f1wb = linb + 262144;                 // 10240
  short* img  = f1wb + 10240;                  // 48640
  float* convW = (float*)(img + 48640);        // 2304
  float* convB = convW + 2304;                 // 256
  float* qkvdw = convB + 256;                  // 1728
  float* qkvdb = qkvdw + 1728;                 // 192

  k_prep<<<1024, 256, 0, stream>>>(f1_w, fpw_w, f2_w, qkv_pw, lin_w,
      fdw_w, fdw_b, f_bng, f_bnb, f_bnm, f_bnv,
      qkv_dw, qkv_bng, qkv_bnb, qkv_bnm, qkv_bnv,
      qkvA, linb, f1wb, img, convW, convB, qkvdw, qkvdb);
  for (int l = 0; l < 2; l++) {
    const float* xin = (l == 0) ? x_in : xbuf;
    k_att3<<<B_, 512, 0, stream>>>(xin, ln1_g + l * 512, ln1_b + l * 512,
        qkvdw + l * 864, qkvdb + l * 96, qkvA + l * 3840,
        position + l * 1024, c1d_w + l * 128, c1d_b + l * 16,
        linb + l * 131072, lin_b + l * 512, xbuf);
    k_ffn4<<<B_, 1024, 0, stream>>>(xbuf, ln2_g + l * 512, ln2_b + l * 512,
        f1wb + l * 5120, f1_b + l * 128, convW + l * 1152, convB + l * 128,
        img + l * 24320, fpw_b + l * 128, f2_b + l * 32, xbuf);
  }
}